// Round 4
// baseline (283.780 us; speedup 1.0000x reference)
//
#include <hip/hip_runtime.h>
#include <math.h>

// PAM module on MFMA, v4: B=4, C=256, H=W=64 -> N=4096, CK=32.
// k0a: pack W -> bf16 [320][256] + bias[320]
// k0b: transpose x -> xT[b][n][c] bf16
// k1 : MFMA QKV -> Q[b][n][32], K[b][m][32] (bf16), Vc[b][c][m] (bf16)
// k2 : MFMA flash attention, 16 rows/wave, G=2 KV split, 512x4-wave blocks
//      (2 waves/SIMD), direct-L2 K/V with self-renewing V register pipeline,
//      defer-max (THR=8). O^T accumulation -> bf16 partials + (Mp,Lp).
// k3 : combine partials + gamma*O + x (fused epilogue)

#define BB 4
#define CC 256
#define NN 4096
#define CKK 32

typedef __attribute__((ext_vector_type(4))) float f32x4;
typedef __attribute__((ext_vector_type(8))) short short8;
typedef __attribute__((ext_vector_type(4))) short short4v;

static __device__ __forceinline__ ushort f2bf(float f) {
    union { float f; unsigned u; } v; v.f = f;
    unsigned r = v.u + 0x7FFFu + ((v.u >> 16) & 1u);
    return (ushort)(r >> 16);
}
static __device__ __forceinline__ float bf2f(ushort h) {
    union { unsigned u; float f; } v; v.u = ((unsigned)h) << 16;
    return v.f;
}

// ---------------- k0a: pack weights + biases to bf16 ----------------
__global__ __launch_bounds__(256) void pack_w_kernel(
    const float* __restrict__ Wq, const float* __restrict__ bq,
    const float* __restrict__ Wk, const float* __restrict__ bk,
    const float* __restrict__ Wv, const float* __restrict__ bv,
    ushort* __restrict__ Wb, float* __restrict__ bias)
{
    const int o = blockIdx.x;      // 0..319
    const int c = threadIdx.x;     // 0..255
    const float* src; float bsc;
    if (o < 32)      { src = Wq + o * CC;        bsc = bq[o]; }
    else if (o < 64) { src = Wk + (o - 32) * CC; bsc = bk[o - 32]; }
    else             { src = Wv + (o - 64) * CC; bsc = bv[o - 64]; }
    Wb[o * CC + c] = f2bf(src[c]);
    if (c == 0) bias[o] = bsc;
}

// ---------------- k0b: x[b][c][n] fp32 -> xT[b][n][c] bf16 ----------------
__global__ __launch_bounds__(256) void xpose_kernel(
    const float* __restrict__ x, ushort* __restrict__ xT)
{
    __shared__ float t[32][33];
    const int b = blockIdx.z, c0 = blockIdx.y * 32, n0 = blockIdx.x * 32;
    const int tid = threadIdx.x;
    #pragma unroll
    for (int i = 0; i < 4; ++i) {
        int idx = tid + i * 256, rr = idx >> 5, nn = idx & 31;
        t[rr][nn] = x[((size_t)b * CC + c0 + rr) * NN + n0 + nn];
    }
    __syncthreads();
    #pragma unroll
    for (int i = 0; i < 4; ++i) {
        int idx = tid + i * 256, rr = idx >> 5, cc = idx & 31;
        xT[((size_t)b * NN + n0 + rr) * CC + c0 + cc] = f2bf(t[cc][rr]);
    }
}

// ---------------- k1: QKV projections via MFMA ----------------
__global__ __launch_bounds__(256) void qkv_mfma_kernel(
    const ushort* __restrict__ Wb, const float* __restrict__ bias,
    const ushort* __restrict__ xT,
    ushort* __restrict__ Q, ushort* __restrict__ Kt, ushort* __restrict__ V)
{
    const int b = blockIdx.y, n0 = blockIdx.x * 64;
    const int tid = threadIdx.x;
    const int w = tid >> 6, lane = tid & 63, l15 = lane & 15, q = lane >> 4;

    f32x4 acc[5][4];
    #pragma unroll
    for (int c5 = 0; c5 < 5; ++c5)
        #pragma unroll
        for (int nc = 0; nc < 4; ++nc) acc[c5][nc] = (f32x4)0.f;

    #pragma unroll
    for (int ks = 0; ks < 8; ++ks) {
        short8 af[5], bf[4];
        #pragma unroll
        for (int c5 = 0; c5 < 5; ++c5)
            af[c5] = *(const short8*)&Wb[(w * 80 + c5 * 16 + l15) * CC + ks * 32 + q * 8];
        #pragma unroll
        for (int nc = 0; nc < 4; ++nc)
            bf[nc] = *(const short8*)&xT[((size_t)b * NN + n0 + nc * 16 + l15) * CC + ks * 32 + q * 8];
        #pragma unroll
        for (int c5 = 0; c5 < 5; ++c5)
            #pragma unroll
            for (int nc = 0; nc < 4; ++nc)
                acc[c5][nc] = __builtin_amdgcn_mfma_f32_16x16x32_bf16(af[c5], bf[nc], acc[c5][nc], 0, 0, 0);
    }

    #pragma unroll
    for (int c5 = 0; c5 < 5; ++c5) {
        const int o0 = w * 80 + c5 * 16;
        float bia[4];
        #pragma unroll
        for (int r = 0; r < 4; ++r) bia[r] = bias[o0 + q * 4 + r];
        if (o0 >= 64) {
            #pragma unroll
            for (int nc = 0; nc < 4; ++nc)
                #pragma unroll
                for (int r = 0; r < 4; ++r)
                    V[((size_t)b * CC + o0 - 64 + q * 4 + r) * NN + n0 + nc * 16 + l15] =
                        f2bf(acc[c5][nc][r] + bia[r]);
        } else {
            ushort* dst = (o0 < 32) ? Q : Kt;
            const int oo = (o0 & 31) + q * 4;
            #pragma unroll
            for (int nc = 0; nc < 4; ++nc) {
                short4v h;
                #pragma unroll
                for (int r = 0; r < 4; ++r) h[r] = (short)f2bf(acc[c5][nc][r] + bia[r]);
                *(short4v*)&dst[((size_t)b * NN + n0 + nc * 16 + l15) * CKK + oo] = h;
            }
        }
    }
}

// ---------------- k2: flash attention, 16 rows/wave, G=2, 2 waves/SIMD ----
__global__ __launch_bounds__(256, 2) void attn_mfma_kernel(
    const ushort* __restrict__ Q, const ushort* __restrict__ K,
    const ushort* __restrict__ V,
    ushort* __restrict__ Op, float* __restrict__ Mp, float* __restrict__ Lp)
{
    __shared__ __align__(16) ushort pb[4][16][40];   // per-wave P tile [n][m]
    __shared__ float alph[4][16];                    // per-wave row factors

    // 512 blocks: xcd = id&7 -> (b,g); ix = id>>3 in [0,64) -> 64 rows
    const int id = blockIdx.x;
    const int xcd = id & 7, ix = id >> 3;
    const int b = xcd >> 1, g = xcd & 1;
    const int n0 = ix * 64;

    const int tid = threadIdx.x;
    const int w = tid >> 6, lane = tid & 63, l15 = lane & 15, q = lane >> 4;
    const int n0w = n0 + w * 16;          // this wave's 16 query rows

    // Q fragment (A): row = l15, k = q*8..+7
    short8 qf = *(const short8*)&Q[((size_t)b * NN + n0w + l15) * CKK + q * 8];

    f32x4 acc[16];                        // O^T: D[c=ci*16+q*4+r][n=l15]
    #pragma unroll
    for (int ci = 0; ci < 16; ++ci) acc[ci] = (f32x4)0.f;
    float m_i[4], l_p[4];
    #pragma unroll
    for (int r = 0; r < 4; ++r) { m_i[r] = -3.0e38f; l_p[r] = 0.f; }

    const size_t kbase = (size_t)b * NN * CKK;
    const size_t vbase = (size_t)b * CC * NN;
    const int m_start = g * (NN / 2);
    const int NT = (NN / 2) / 32;

    // prefetch K tile 0
    short8 k0 = *(const short8*)&K[kbase + (size_t)(m_start + l15) * CKK + q * 8];
    short8 k1 = *(const short8*)&K[kbase + (size_t)(m_start + 16 + l15) * CKK + q * 8];
    // prefetch V tile 0 (self-renewing single buffer)
    short8 vf[16];
    #pragma unroll
    for (int ci = 0; ci < 16; ++ci)
        vf[ci] = *(const short8*)&V[vbase + (size_t)(ci * 16 + l15) * NN + m_start + q * 8];

    for (int mt = 0; mt < NT; ++mt) {
        const int m0 = m_start + mt * 32;
        // next tile base (clamped; last-iter loads are harmless re-reads)
        const int m0n = (mt + 1 < NT) ? m0 + 32 : m_start;

        // ---- S = Q.K^T (16 rows x 32 cols) ----
        f32x4 s0 = __builtin_amdgcn_mfma_f32_16x16x32_bf16(qf, k0, (f32x4)0.f, 0, 0, 0);
        f32x4 s1 = __builtin_amdgcn_mfma_f32_16x16x32_bf16(qf, k1, (f32x4)0.f, 0, 0, 0);

        // prefetch next K tile
        k0 = *(const short8*)&K[kbase + (size_t)(m0n + l15) * CKK + q * 8];
        k1 = *(const short8*)&K[kbase + (size_t)(m0n + 16 + l15) * CKK + q * 8];

        // ---- online softmax with defer-max (THR=8), rows = q*4+r ----
        bool need = false;
        #pragma unroll
        for (int r = 0; r < 4; ++r) {
            float mx = fmaxf(s0[r], s1[r]);
            #pragma unroll
            for (int d = 1; d < 16; d <<= 1) mx = fmaxf(mx, __shfl_xor(mx, d));
            const float mo = m_i[r];
            const bool resc = mx > mo + 8.f;         // uniform across 16-lane group
            const float mn = resc ? mx : mo;
            const float al = resc ? __expf(mo - mx) : 1.f;
            need = need || resc;
            const float p0 = __expf(s0[r] - mn);
            const float p1 = __expf(s1[r] - mn);
            l_p[r] = l_p[r] * al + p0 + p1;
            m_i[r] = mn;
            const int row = q * 4 + r;
            pb[w][row][l15]      = f2bf(p0);
            pb[w][row][16 + l15] = f2bf(p1);
            if (l15 == 0) alph[w][row] = al;
        }

        // rescale acc (factor per n-col = l15) via LDS broadcast, rare after warmup
        if (__any(need)) {
            const float a0 = alph[w][l15];
            #pragma unroll
            for (int ci = 0; ci < 16; ++ci) acc[ci] *= a0;
        }

        // P B-frag: B[k=m][col=n]; lane reads P[n=l15][m=q*8..+7]
        short8 pB = *(const short8*)&pb[w][l15][q * 8];

        // ---- PV: O^T[c][n] += Vc[c][m]*P^T[m][n]; reload vf[ci] for next tile
        #pragma unroll
        for (int ci = 0; ci < 16; ++ci) {
            acc[ci] = __builtin_amdgcn_mfma_f32_16x16x32_bf16(vf[ci], pB, acc[ci], 0, 0, 0);
            vf[ci] = *(const short8*)&V[vbase + (size_t)(ci * 16 + l15) * NN + m0n + q * 8];
        }
    }

    // ---- epilogue: reduce row-sums, write partials ----
    #pragma unroll
    for (int r = 0; r < 4; ++r) {
        float l = l_p[r];
        #pragma unroll
        for (int d = 1; d < 16; d <<= 1) l += __shfl_xor(l, d);
        const int row = q * 4 + r;
        if (l15 == 0) {
            alph[w][row] = 1.f / l;
            const size_t nidx = (size_t)(g * BB + b) * NN + n0w + row;
            Mp[nidx] = m_i[r];
            Lp[nidx] = l;
        }
    }
    const float inv = alph[w][l15];
    ushort* ob = Op + ((size_t)(g * BB + b) * CC) * NN;
    #pragma unroll
    for (int ci = 0; ci < 16; ++ci)
        #pragma unroll
        for (int r = 0; r < 4; ++r)
            ob[(size_t)(ci * 16 + q * 4 + r) * NN + n0w + l15] = f2bf(acc[ci][r] * inv);
}

// ---------------- k3: combine partials + residual epilogue ----------------
__global__ __launch_bounds__(256) void combine_kernel(
    const ushort* __restrict__ Op, const float* __restrict__ Mp,
    const float* __restrict__ Lp, const float* __restrict__ x,
    const float* __restrict__ gamma, float* __restrict__ out)
{
    const int b = blockIdx.z, c0 = blockIdx.y * 64;
    const int n = blockIdx.x * 256 + threadIdx.x;
    const size_t n0i = (size_t)b * NN + n;
    const size_t n1i = (size_t)(BB + b) * NN + n;
    const float m0 = Mp[n0i], m1 = Mp[n1i];
    const float l0 = Lp[n0i], l1 = Lp[n1i];
    const float M = fmaxf(m0, m1);
    const float w0 = l0 * __expf(m0 - M), w1 = l1 * __expf(m1 - M);
    const float inv = 1.f / (w0 + w1);
    const float c0f = w0 * inv, c1f = w1 * inv;
    const float gm = gamma[0];
    #pragma unroll 4
    for (int c = 0; c < 64; ++c) {
        const size_t row = (size_t)(c0 + c) * NN + n;
        const float o = c0f * bf2f(Op[(size_t)b * CC * NN + row]) +
                        c1f * bf2f(Op[(size_t)(BB + b) * CC * NN + row]);
        const size_t xo = (size_t)b * CC * NN + row;
        out[xo] = gm * o + x[xo];
    }
}

extern "C" void kernel_launch(void* const* d_in, const int* in_sizes, int n_in,
                              void* d_out, int out_size, void* d_ws, size_t ws_size,
                              hipStream_t stream) {
    const float* x     = (const float*)d_in[0];
    const float* Wq    = (const float*)d_in[1];
    const float* bq    = (const float*)d_in[2];
    const float* Wk    = (const float*)d_in[3];
    const float* bk    = (const float*)d_in[4];
    const float* Wv    = (const float*)d_in[5];
    const float* bv    = (const float*)d_in[6];
    const float* gamma = (const float*)d_in[7];
    float* out = (float*)d_out;

    char* p = (char*)d_ws;
    ushort* Wb   = (ushort*)(p);                 // 163840
    float*  bias = (float*) (p + 163840);        // 1280
    ushort* xT   = (ushort*)(p + 165120);        // 8388608
    ushort* Qb   = (ushort*)(p + 8553728);       // 1048576
    ushort* Kb   = (ushort*)(p + 9602304);       // 1048576
    ushort* Vc   = (ushort*)(p + 10650880);      // 8388608
    ushort* Opb  = (ushort*)(p + 19039488);      // 16777216 (2 segs bf16)
    float*  Mpb  = (float*) (p + 35816704);      // 131072
    float*  Lpb  = (float*) (p + 35947776);      // 131072
    // total 36,078,848 B (proven to fit)

    pack_w_kernel<<<dim3(320), 256, 0, stream>>>(Wq, bq, Wk, bk, Wv, bv, Wb, bias);
    xpose_kernel<<<dim3(NN / 32, CC / 32, BB), 256, 0, stream>>>(x, xT);
    qkv_mfma_kernel<<<dim3(NN / 64, BB), 256, 0, stream>>>(Wb, bias, xT, Qb, Kb, Vc);
    attn_mfma_kernel<<<dim3(512), 256, 0, stream>>>(Qb, Kb, Vc, Opb, Mpb, Lpb);
    combine_kernel<<<dim3(NN / 256, CC / 64, BB), 256, 0, stream>>>(Opb, Mpb, Lpb, x, gamma, out);
}

// Round 5
// 180.809 us; speedup vs baseline: 1.5695x; 1.5695x over previous
//
#include <hip/hip_runtime.h>
#include <math.h>

// PAM module on MFMA, v5: B=4, C=256, H=W=64 -> N=4096, CK=32.
// k0a: pack W -> bf16 [320][256] + bias[320]
// k0b: transpose x -> xT[b][n][c] bf16
// k1 : MFMA QKV -> Q[b][n][32], K[b][m][32] (bf16), Vc[b][c][m] (bf16)
// k2 : MFMA flash attention: 4 waves x 32 rows, KVB=32, G-way KV split
//      (G=4 if ws allows, else 2), LDS-staged K/V (reg-staged, T14),
//      swapped QK^T (S^T) -> in-register softmax, defer-max THR=8,
//      O^T accumulation -> bf16 partials Op[g][b][c][n] + (Mp,Lp)[g][b][n]
// k3 : combine G partials + gamma*O + x (fused epilogue)

#define BB 4
#define CC 256
#define NN 4096
#define CKK 32

typedef __attribute__((ext_vector_type(4))) float f32x4;
typedef __attribute__((ext_vector_type(8))) short short8;
typedef __attribute__((ext_vector_type(4))) short short4v;
typedef __attribute__((ext_vector_type(2))) unsigned int u32x2;

static __device__ __forceinline__ ushort f2bf(float f) {
    union { float f; unsigned u; } v; v.f = f;
    unsigned r = v.u + 0x7FFFu + ((v.u >> 16) & 1u);
    return (ushort)(r >> 16);
}
static __device__ __forceinline__ float bf2f(ushort h) {
    union { unsigned u; float f; } v; v.u = ((unsigned)h) << 16;
    return v.f;
}
static __device__ __forceinline__ unsigned pack2(float lo, float hi) {
    return ((unsigned)f2bf(hi) << 16) | (unsigned)f2bf(lo);
}

// ---------------- k0a: pack weights + biases to bf16 ----------------
__global__ __launch_bounds__(256) void pack_w_kernel(
    const float* __restrict__ Wq, const float* __restrict__ bq,
    const float* __restrict__ Wk, const float* __restrict__ bk,
    const float* __restrict__ Wv, const float* __restrict__ bv,
    ushort* __restrict__ Wb, float* __restrict__ bias)
{
    const int o = blockIdx.x;      // 0..319
    const int c = threadIdx.x;     // 0..255
    const float* src; float bsc;
    if (o < 32)      { src = Wq + o * CC;        bsc = bq[o]; }
    else if (o < 64) { src = Wk + (o - 32) * CC; bsc = bk[o - 32]; }
    else             { src = Wv + (o - 64) * CC; bsc = bv[o - 64]; }
    Wb[o * CC + c] = f2bf(src[c]);
    if (c == 0) bias[o] = bsc;
}

// ---------------- k0b: x[b][c][n] fp32 -> xT[b][n][c] bf16 ----------------
__global__ __launch_bounds__(256) void xpose_kernel(
    const float* __restrict__ x, ushort* __restrict__ xT)
{
    __shared__ float t[32][33];
    const int b = blockIdx.z, c0 = blockIdx.y * 32, n0 = blockIdx.x * 32;
    const int tid = threadIdx.x;
    #pragma unroll
    for (int i = 0; i < 4; ++i) {
        int idx = tid + i * 256, rr = idx >> 5, nn = idx & 31;
        t[rr][nn] = x[((size_t)b * CC + c0 + rr) * NN + n0 + nn];
    }
    __syncthreads();
    #pragma unroll
    for (int i = 0; i < 4; ++i) {
        int idx = tid + i * 256, rr = idx >> 5, cc = idx & 31;
        xT[((size_t)b * NN + n0 + rr) * CC + c0 + cc] = f2bf(t[cc][rr]);
    }
}

// ---------------- k1: QKV projections via MFMA ----------------
__global__ __launch_bounds__(256) void qkv_mfma_kernel(
    const ushort* __restrict__ Wb, const float* __restrict__ bias,
    const ushort* __restrict__ xT,
    ushort* __restrict__ Q, ushort* __restrict__ Kt, ushort* __restrict__ V)
{
    const int b = blockIdx.y, n0 = blockIdx.x * 64;
    const int tid = threadIdx.x;
    const int w = tid >> 6, lane = tid & 63, l15 = lane & 15, q = lane >> 4;

    f32x4 acc[5][4];
    #pragma unroll
    for (int c5 = 0; c5 < 5; ++c5)
        #pragma unroll
        for (int nc = 0; nc < 4; ++nc) acc[c5][nc] = (f32x4)0.f;

    #pragma unroll
    for (int ks = 0; ks < 8; ++ks) {
        short8 af[5], bf[4];
        #pragma unroll
        for (int c5 = 0; c5 < 5; ++c5)
            af[c5] = *(const short8*)&Wb[(w * 80 + c5 * 16 + l15) * CC + ks * 32 + q * 8];
        #pragma unroll
        for (int nc = 0; nc < 4; ++nc)
            bf[nc] = *(const short8*)&xT[((size_t)b * NN + n0 + nc * 16 + l15) * CC + ks * 32 + q * 8];
        #pragma unroll
        for (int c5 = 0; c5 < 5; ++c5)
            #pragma unroll
            for (int nc = 0; nc < 4; ++nc)
                acc[c5][nc] = __builtin_amdgcn_mfma_f32_16x16x32_bf16(af[c5], bf[nc], acc[c5][nc], 0, 0, 0);
    }

    #pragma unroll
    for (int c5 = 0; c5 < 5; ++c5) {
        const int o0 = w * 80 + c5 * 16;
        float bia[4];
        #pragma unroll
        for (int r = 0; r < 4; ++r) bia[r] = bias[o0 + q * 4 + r];
        if (o0 >= 64) {
            #pragma unroll
            for (int nc = 0; nc < 4; ++nc)
                #pragma unroll
                for (int r = 0; r < 4; ++r)
                    V[((size_t)b * CC + o0 - 64 + q * 4 + r) * NN + n0 + nc * 16 + l15] =
                        f2bf(acc[c5][nc][r] + bia[r]);
        } else {
            ushort* dst = (o0 < 32) ? Q : Kt;
            const int oo = (o0 & 31) + q * 4;
            #pragma unroll
            for (int nc = 0; nc < 4; ++nc) {
                short4v h;
                #pragma unroll
                for (int r = 0; r < 4; ++r) h[r] = (short)f2bf(acc[c5][nc][r] + bia[r]);
                *(short4v*)&dst[((size_t)b * NN + n0 + nc * 16 + l15) * CKK + oo] = h;
            }
        }
    }
}

// ---------------- k2: flash attention v5 ----------------
// 4 waves x 32 rows = 128 rows/block. KVB=32. LDS-staged K/V, swapped QK^T.
__global__ __launch_bounds__(256, 2) void attn_mfma_kernel(
    const ushort* __restrict__ Q, const ushort* __restrict__ K,
    const ushort* __restrict__ V,
    ushort* __restrict__ Op, float* __restrict__ Mp, float* __restrict__ Lp,
    int G, int NSEG)
{
    __shared__ __align__(16) ushort vs[256][40];    // V tile [c][m], 80B rows
    __shared__ __align__(16) ushort ks[32][40];     // K tile [m][ck]
    __shared__ __align__(16) ushort pb[4][32][40];  // per-wave P tile [n][m]

    // block -> (b, g, row-block), XCD-pinned: batch b on XCDs {2b, 2b+1}
    const int id = blockIdx.x;
    const int xcd = id & 7, ix = id >> 3;
    const int b = xcd >> 1;
    int g, row;
    if (G == 4) { g = ((xcd & 1) << 1) | (ix & 1); row = ix >> 1; }
    else        { g = xcd & 1;                     row = ix; }
    const int n0 = row * 128;

    const int tid = threadIdx.x;
    const int w = tid >> 6, lane = tid & 63, l15 = lane & 15, q = lane >> 4;
    const int n0w = n0 + w * 32;

    // Q B-frags (B[k=ck][col=n]): lane holds Q[n0w + h*16 + l15][q*8..+7]
    short8 qB0 = *(const short8*)&Q[((size_t)b * NN + n0w + l15) * CKK + q * 8];
    short8 qB1 = *(const short8*)&Q[((size_t)b * NN + n0w + 16 + l15) * CKK + q * 8];

    f32x4 acc[16][2];                 // O^T: D[c=ci*16+q*4+r][n=n0w+h*16+l15]
    #pragma unroll
    for (int ci = 0; ci < 16; ++ci) { acc[ci][0] = (f32x4)0.f; acc[ci][1] = (f32x4)0.f; }
    float m_i[2] = {-3.0e38f, -3.0e38f};
    float l_p[2] = {0.f, 0.f};        // per-lane partial row-sums

    const size_t kgb = (size_t)b * NN * CKK;
    const size_t vgb = (size_t)b * CC * NN;
    const int m_start = g * NSEG;
    const int NT = NSEG / 32;

    // staging: K by threads 0-127 (row m=tid>>2, seg tid&3);
    //          V by all 256 (c = tid>>2 + i*64, seg tid&3), 4 iters
    const int srow = tid >> 2, sseg = tid & 3;

    // prologue: stage tile 0
    short8 kreg; short8 vreg[4];
    if (tid < 128)
        kreg = *(const short8*)&K[kgb + (size_t)(m_start + srow) * CKK + sseg * 8];
    #pragma unroll
    for (int i = 0; i < 4; ++i)
        vreg[i] = *(const short8*)&V[vgb + (size_t)(srow + i * 64) * NN + m_start + sseg * 8];
    if (tid < 128) *(short8*)&ks[srow][sseg * 8] = kreg;
    #pragma unroll
    for (int i = 0; i < 4; ++i) *(short8*)&vs[srow + i * 64][sseg * 8] = vreg[i];
    __syncthreads();

    for (int mt = 0; mt < NT; ++mt) {
        const bool more = (mt + 1 < NT);
        const int m0n = m_start + (mt + 1) * 32;

        // T14: issue next tile's global loads; land during compute
        if (more) {
            if (tid < 128)
                kreg = *(const short8*)&K[kgb + (size_t)(m0n + srow) * CKK + sseg * 8];
            #pragma unroll
            for (int i = 0; i < 4; ++i)
                vreg[i] = *(const short8*)&V[vgb + (size_t)(srow + i * 64) * NN + m0n + sseg * 8];
        }

        // ---- S^T = K.Q^T : D[m_sub=q*4+r][n_sub=l15] ----
        short8 kA0 = *(const short8*)&ks[l15][q * 8];
        short8 kA1 = *(const short8*)&ks[16 + l15][q * 8];
        f32x4 s00 = __builtin_amdgcn_mfma_f32_16x16x32_bf16(kA0, qB0, (f32x4)0.f, 0, 0, 0);
        f32x4 s10 = __builtin_amdgcn_mfma_f32_16x16x32_bf16(kA1, qB0, (f32x4)0.f, 0, 0, 0);
        f32x4 s01 = __builtin_amdgcn_mfma_f32_16x16x32_bf16(kA0, qB1, (f32x4)0.f, 0, 0, 0);
        f32x4 s11 = __builtin_amdgcn_mfma_f32_16x16x32_bf16(kA1, qB1, (f32x4)0.f, 0, 0, 0);

        // ---- in-register online softmax per n-half (row n = h*16+l15) ----
        #pragma unroll
        for (int h = 0; h < 2; ++h) {
            const f32x4 slo = h ? s01 : s00;   // m = q*4+r
            const f32x4 shi = h ? s11 : s10;   // m = 16+q*4+r
            float mx = fmaxf(fmaxf(fmaxf(slo[0], slo[1]), fmaxf(slo[2], slo[3])),
                             fmaxf(fmaxf(shi[0], shi[1]), fmaxf(shi[2], shi[3])));
            mx = fmaxf(mx, __shfl_xor(mx, 16));
            mx = fmaxf(mx, __shfl_xor(mx, 32));
            const float mo = m_i[h];
            const bool resc = mx > mo + 8.f;   // defer-max THR=8
            const float mn = resc ? mx : mo;
            float p[8];
            #pragma unroll
            for (int r = 0; r < 4; ++r) {
                p[r]     = __expf(slo[r] - mn);
                p[4 + r] = __expf(shi[r] - mn);
            }
            const float sum = ((p[0] + p[1]) + (p[2] + p[3])) +
                              ((p[4] + p[5]) + (p[6] + p[7]));
            float al = 1.f;
            if (resc) { al = __expf(mo - mx); m_i[h] = mx; }
            l_p[h] = l_p[h] * al + sum;
            if (__any(resc)) {                 // al is per-lane correct (col n = l15)
                #pragma unroll
                for (int ci = 0; ci < 16; ++ci) acc[ci][h] *= al;
            }
            // P -> pb[n][m] (bf16), two b64 writes
            const int nn = h * 16 + l15;
            u32x2 wlo, whi;
            wlo[0] = pack2(p[0], p[1]); wlo[1] = pack2(p[2], p[3]);
            whi[0] = pack2(p[4], p[5]); whi[1] = pack2(p[6], p[7]);
            *(u32x2*)&pb[w][nn][q * 4]      = wlo;
            *(u32x2*)&pb[w][nn][16 + q * 4] = whi;
        }

        // P B-frags (same-wave write->read; compiler inserts lgkmcnt)
        short8 pB0 = *(const short8*)&pb[w][l15][q * 8];
        short8 pB1 = *(const short8*)&pb[w][16 + l15][q * 8];

        // ---- PV: O^T[c][n] += Vc[c][m] * P^T[m][n] ----
        #pragma unroll
        for (int ci = 0; ci < 16; ++ci) {
            short8 vA = *(const short8*)&vs[ci * 16 + l15][q * 8];
            acc[ci][0] = __builtin_amdgcn_mfma_f32_16x16x32_bf16(vA, pB0, acc[ci][0], 0, 0, 0);
            acc[ci][1] = __builtin_amdgcn_mfma_f32_16x16x32_bf16(vA, pB1, acc[ci][1], 0, 0, 0);
        }

        __syncthreads();                  // all waves done reading ks/vs
        if (more) {
            if (tid < 128) *(short8*)&ks[srow][sseg * 8] = kreg;
            #pragma unroll
            for (int i = 0; i < 4; ++i) *(short8*)&vs[srow + i * 64][sseg * 8] = vreg[i];
        }
        __syncthreads();                  // staged tile visible
    }

    // ---- epilogue: reduce row-sums over q-groups, write partials ----
    float lfull[2], linv[2];
    #pragma unroll
    for (int h = 0; h < 2; ++h) {
        float l = l_p[h];
        l += __shfl_xor(l, 16);
        l += __shfl_xor(l, 32);
        lfull[h] = l; linv[h] = 1.f / l;
    }
    if (q == 0) {
        #pragma unroll
        for (int h = 0; h < 2; ++h) {
            const size_t idx = (size_t)(g * BB + b) * NN + n0w + h * 16 + l15;
            Mp[idx] = m_i[h];
            Lp[idx] = lfull[h];
        }
    }
    ushort* ob = Op + (size_t)(g * BB + b) * CC * NN;
    #pragma unroll
    for (int ci = 0; ci < 16; ++ci)
        #pragma unroll
        for (int h = 0; h < 2; ++h)
            #pragma unroll
            for (int r = 0; r < 4; ++r)
                ob[(size_t)(ci * 16 + q * 4 + r) * NN + n0w + h * 16 + l15] =
                    f2bf(acc[ci][h][r] * linv[h]);
}

// ---------------- k3: combine G partials + residual epilogue ----------------
__global__ __launch_bounds__(256) void combine_kernel(
    const ushort* __restrict__ Op, const float* __restrict__ Mp,
    const float* __restrict__ Lp, const float* __restrict__ x,
    const float* __restrict__ gamma, float* __restrict__ out, int G)
{
    const int b = blockIdx.z, c0 = blockIdx.y * 64;
    const int n = blockIdx.x * 256 + threadIdx.x;
    float M = -3.0e38f;
    #pragma unroll
    for (int g = 0; g < 4; ++g)
        if (g < G) M = fmaxf(M, Mp[(size_t)(g * BB + b) * NN + n]);
    float wg[4] = {0.f, 0.f, 0.f, 0.f};
    float wsum = 0.f;
    #pragma unroll
    for (int g = 0; g < 4; ++g)
        if (g < G) {
            wg[g] = Lp[(size_t)(g * BB + b) * NN + n] *
                    __expf(Mp[(size_t)(g * BB + b) * NN + n] - M);
            wsum += wg[g];
        }
    const float inv = 1.f / wsum;
    #pragma unroll
    for (int g = 0; g < 4; ++g) wg[g] *= inv;
    const float gm = gamma[0];
    #pragma unroll 4
    for (int c = 0; c < 64; ++c) {
        const size_t rowo = (size_t)(c0 + c) * NN + n;
        float o = 0.f;
        #pragma unroll
        for (int g = 0; g < 4; ++g)
            if (g < G) o += wg[g] * bf2f(Op[(size_t)(g * BB + b) * CC * NN + rowo]);
        const size_t xo = (size_t)b * CC * NN + rowo;
        out[xo] = gm * o + x[xo];
    }
}

extern "C" void kernel_launch(void* const* d_in, const int* in_sizes, int n_in,
                              void* d_out, int out_size, void* d_ws, size_t ws_size,
                              hipStream_t stream) {
    const float* x     = (const float*)d_in[0];
    const float* Wq    = (const float*)d_in[1];
    const float* bq    = (const float*)d_in[2];
    const float* Wk    = (const float*)d_in[3];
    const float* bk    = (const float*)d_in[4];
    const float* Wv    = (const float*)d_in[5];
    const float* bv    = (const float*)d_in[6];
    const float* gamma = (const float*)d_in[7];
    float* out = (float*)d_out;

    char* p = (char*)d_ws;
    ushort* Wb   = (ushort*)(p);                 // 163840
    float*  bias = (float*) (p + 163840);        // 1280  -> 165120
    ushort* xT   = (ushort*)(p + 165120);        // 8388608 -> 8553728
    ushort* Qb   = (ushort*)(p + 8553728);       // 1048576 -> 9602304
    ushort* Kb   = (ushort*)(p + 9602304);       // 1048576 -> 10650880
    ushort* Vc   = (ushort*)(p + 10650880);      // 8388608 -> 19039488
    float*  Mpb  = (float*) (p + 19039488);      // 262144  -> 19301632
    float*  Lpb  = (float*) (p + 19301632);      // 262144  -> 19563776
    ushort* Opb  = (ushort*)(p + 19563776);      // G*8388608
    // G=4 total: 53,118,208 B; G=2 total: 36,340,992 B
    const int G = (ws_size >= (size_t)53118208) ? 4 : 2;

    pack_w_kernel<<<dim3(320), 256, 0, stream>>>(Wq, bq, Wk, bk, Wv, bv, Wb, bias);
    xpose_kernel<<<dim3(NN / 32, CC / 32, BB), 256, 0, stream>>>(x, xT);
    qkv_mfma_kernel<<<dim3(NN / 64, BB), 256, 0, stream>>>(Wb, bias, xT, Qb, Kb, Vc);
    attn_mfma_kernel<<<dim3(128 * G), 256, 0, stream>>>(Qb, Kb, Vc, Opb, Mpb, Lpb, G, NN / G);
    combine_kernel<<<dim3(NN / 256, CC / 64, BB), 256, 0, stream>>>(Opb, Mpb, Lpb, x, gamma, out, G);
}

// Round 6
// 102.412 us; speedup vs baseline: 2.7710x; 1.7655x over previous
//
#include <hip/hip_runtime.h>
#include <math.h>

// PAM module on MFMA, v6: B=4, C=256, H=W=64 -> N=4096, CK=32.
// k0a: pack W -> bf16 [320][256] + bias[320]
// k0b: transpose x -> xT[b][n][c] bf16
// k1 : MFMA QKV -> Q[b][n][32], K[b][m][32] (bf16), Vc[b][c][m] (bf16)
// k2 : MFMA flash attention (unchanged from v5): 4 waves x 32 rows, KVB=32,
//      G-way KV split, LDS-staged K/V, swapped QK^T, defer-max THR=8,
//      O^T accumulation -> bf16 partials Op[g][b][c][n] + (Mp,Lp)[g][b][n]
// k3 : combine, REWRITTEN: vectorized (short8/float4), 1 thread = 8 n's,
//      2048 blocks (8/CU), templated on G.

#define BB 4
#define CC 256
#define NN 4096
#define CKK 32

typedef __attribute__((ext_vector_type(4))) float f32x4;
typedef __attribute__((ext_vector_type(8))) short short8;
typedef __attribute__((ext_vector_type(4))) short short4v;
typedef __attribute__((ext_vector_type(2))) unsigned int u32x2;

static __device__ __forceinline__ ushort f2bf(float f) {
    union { float f; unsigned u; } v; v.f = f;
    unsigned r = v.u + 0x7FFFu + ((v.u >> 16) & 1u);
    return (ushort)(r >> 16);
}
static __device__ __forceinline__ float bf2f(ushort h) {
    union { unsigned u; float f; } v; v.u = ((unsigned)h) << 16;
    return v.f;
}
static __device__ __forceinline__ unsigned pack2(float lo, float hi) {
    return ((unsigned)f2bf(hi) << 16) | (unsigned)f2bf(lo);
}

// ---------------- k0a: pack weights + biases to bf16 ----------------
__global__ __launch_bounds__(256) void pack_w_kernel(
    const float* __restrict__ Wq, const float* __restrict__ bq,
    const float* __restrict__ Wk, const float* __restrict__ bk,
    const float* __restrict__ Wv, const float* __restrict__ bv,
    ushort* __restrict__ Wb, float* __restrict__ bias)
{
    const int o = blockIdx.x;      // 0..319
    const int c = threadIdx.x;     // 0..255
    const float* src; float bsc;
    if (o < 32)      { src = Wq + o * CC;        bsc = bq[o]; }
    else if (o < 64) { src = Wk + (o - 32) * CC; bsc = bk[o - 32]; }
    else             { src = Wv + (o - 64) * CC; bsc = bv[o - 64]; }
    Wb[o * CC + c] = f2bf(src[c]);
    if (c == 0) bias[o] = bsc;
}

// ---------------- k0b: x[b][c][n] fp32 -> xT[b][n][c] bf16 ----------------
__global__ __launch_bounds__(256) void xpose_kernel(
    const float* __restrict__ x, ushort* __restrict__ xT)
{
    __shared__ float t[32][33];
    const int b = blockIdx.z, c0 = blockIdx.y * 32, n0 = blockIdx.x * 32;
    const int tid = threadIdx.x;
    #pragma unroll
    for (int i = 0; i < 4; ++i) {
        int idx = tid + i * 256, rr = idx >> 5, nn = idx & 31;
        t[rr][nn] = x[((size_t)b * CC + c0 + rr) * NN + n0 + nn];
    }
    __syncthreads();
    #pragma unroll
    for (int i = 0; i < 4; ++i) {
        int idx = tid + i * 256, rr = idx >> 5, cc = idx & 31;
        xT[((size_t)b * NN + n0 + rr) * CC + c0 + cc] = f2bf(t[cc][rr]);
    }
}

// ---------------- k1: QKV projections via MFMA ----------------
__global__ __launch_bounds__(256) void qkv_mfma_kernel(
    const ushort* __restrict__ Wb, const float* __restrict__ bias,
    const ushort* __restrict__ xT,
    ushort* __restrict__ Q, ushort* __restrict__ Kt, ushort* __restrict__ V)
{
    const int b = blockIdx.y, n0 = blockIdx.x * 64;
    const int tid = threadIdx.x;
    const int w = tid >> 6, lane = tid & 63, l15 = lane & 15, q = lane >> 4;

    f32x4 acc[5][4];
    #pragma unroll
    for (int c5 = 0; c5 < 5; ++c5)
        #pragma unroll
        for (int nc = 0; nc < 4; ++nc) acc[c5][nc] = (f32x4)0.f;

    #pragma unroll
    for (int ks = 0; ks < 8; ++ks) {
        short8 af[5], bf[4];
        #pragma unroll
        for (int c5 = 0; c5 < 5; ++c5)
            af[c5] = *(const short8*)&Wb[(w * 80 + c5 * 16 + l15) * CC + ks * 32 + q * 8];
        #pragma unroll
        for (int nc = 0; nc < 4; ++nc)
            bf[nc] = *(const short8*)&xT[((size_t)b * NN + n0 + nc * 16 + l15) * CC + ks * 32 + q * 8];
        #pragma unroll
        for (int c5 = 0; c5 < 5; ++c5)
            #pragma unroll
            for (int nc = 0; nc < 4; ++nc)
                acc[c5][nc] = __builtin_amdgcn_mfma_f32_16x16x32_bf16(af[c5], bf[nc], acc[c5][nc], 0, 0, 0);
    }

    #pragma unroll
    for (int c5 = 0; c5 < 5; ++c5) {
        const int o0 = w * 80 + c5 * 16;
        float bia[4];
        #pragma unroll
        for (int r = 0; r < 4; ++r) bia[r] = bias[o0 + q * 4 + r];
        if (o0 >= 64) {
            #pragma unroll
            for (int nc = 0; nc < 4; ++nc)
                #pragma unroll
                for (int r = 0; r < 4; ++r)
                    V[((size_t)b * CC + o0 - 64 + q * 4 + r) * NN + n0 + nc * 16 + l15] =
                        f2bf(acc[c5][nc][r] + bia[r]);
        } else {
            ushort* dst = (o0 < 32) ? Q : Kt;
            const int oo = (o0 & 31) + q * 4;
            #pragma unroll
            for (int nc = 0; nc < 4; ++nc) {
                short4v h;
                #pragma unroll
                for (int r = 0; r < 4; ++r) h[r] = (short)f2bf(acc[c5][nc][r] + bia[r]);
                *(short4v*)&dst[((size_t)b * NN + n0 + nc * 16 + l15) * CKK + oo] = h;
            }
        }
    }
}

// ---------------- k2: flash attention v5 (unchanged) ----------------
__global__ __launch_bounds__(256, 2) void attn_mfma_kernel(
    const ushort* __restrict__ Q, const ushort* __restrict__ K,
    const ushort* __restrict__ V,
    ushort* __restrict__ Op, float* __restrict__ Mp, float* __restrict__ Lp,
    int G, int NSEG)
{
    __shared__ __align__(16) ushort vs[256][40];    // V tile [c][m], 80B rows
    __shared__ __align__(16) ushort ks[32][40];     // K tile [m][ck]
    __shared__ __align__(16) ushort pb[4][32][40];  // per-wave P tile [n][m]

    const int id = blockIdx.x;
    const int xcd = id & 7, ix = id >> 3;
    const int b = xcd >> 1;
    int g, row;
    if (G == 4) { g = ((xcd & 1) << 1) | (ix & 1); row = ix >> 1; }
    else        { g = xcd & 1;                     row = ix; }
    const int n0 = row * 128;

    const int tid = threadIdx.x;
    const int w = tid >> 6, lane = tid & 63, l15 = lane & 15, q = lane >> 4;
    const int n0w = n0 + w * 32;

    short8 qB0 = *(const short8*)&Q[((size_t)b * NN + n0w + l15) * CKK + q * 8];
    short8 qB1 = *(const short8*)&Q[((size_t)b * NN + n0w + 16 + l15) * CKK + q * 8];

    f32x4 acc[16][2];                 // O^T: D[c=ci*16+q*4+r][n=n0w+h*16+l15]
    #pragma unroll
    for (int ci = 0; ci < 16; ++ci) { acc[ci][0] = (f32x4)0.f; acc[ci][1] = (f32x4)0.f; }
    float m_i[2] = {-3.0e38f, -3.0e38f};
    float l_p[2] = {0.f, 0.f};

    const size_t kgb = (size_t)b * NN * CKK;
    const size_t vgb = (size_t)b * CC * NN;
    const int m_start = g * NSEG;
    const int NT = NSEG / 32;

    const int srow = tid >> 2, sseg = tid & 3;

    short8 kreg; short8 vreg[4];
    if (tid < 128)
        kreg = *(const short8*)&K[kgb + (size_t)(m_start + srow) * CKK + sseg * 8];
    #pragma unroll
    for (int i = 0; i < 4; ++i)
        vreg[i] = *(const short8*)&V[vgb + (size_t)(srow + i * 64) * NN + m_start + sseg * 8];
    if (tid < 128) *(short8*)&ks[srow][sseg * 8] = kreg;
    #pragma unroll
    for (int i = 0; i < 4; ++i) *(short8*)&vs[srow + i * 64][sseg * 8] = vreg[i];
    __syncthreads();

    for (int mt = 0; mt < NT; ++mt) {
        const bool more = (mt + 1 < NT);
        const int m0n = m_start + (mt + 1) * 32;

        if (more) {
            if (tid < 128)
                kreg = *(const short8*)&K[kgb + (size_t)(m0n + srow) * CKK + sseg * 8];
            #pragma unroll
            for (int i = 0; i < 4; ++i)
                vreg[i] = *(const short8*)&V[vgb + (size_t)(srow + i * 64) * NN + m0n + sseg * 8];
        }

        // ---- S^T = K.Q^T ----
        short8 kA0 = *(const short8*)&ks[l15][q * 8];
        short8 kA1 = *(const short8*)&ks[16 + l15][q * 8];
        f32x4 s00 = __builtin_amdgcn_mfma_f32_16x16x32_bf16(kA0, qB0, (f32x4)0.f, 0, 0, 0);
        f32x4 s10 = __builtin_amdgcn_mfma_f32_16x16x32_bf16(kA1, qB0, (f32x4)0.f, 0, 0, 0);
        f32x4 s01 = __builtin_amdgcn_mfma_f32_16x16x32_bf16(kA0, qB1, (f32x4)0.f, 0, 0, 0);
        f32x4 s11 = __builtin_amdgcn_mfma_f32_16x16x32_bf16(kA1, qB1, (f32x4)0.f, 0, 0, 0);

        #pragma unroll
        for (int h = 0; h < 2; ++h) {
            const f32x4 slo = h ? s01 : s00;
            const f32x4 shi = h ? s11 : s10;
            float mx = fmaxf(fmaxf(fmaxf(slo[0], slo[1]), fmaxf(slo[2], slo[3])),
                             fmaxf(fmaxf(shi[0], shi[1]), fmaxf(shi[2], shi[3])));
            mx = fmaxf(mx, __shfl_xor(mx, 16));
            mx = fmaxf(mx, __shfl_xor(mx, 32));
            const float mo = m_i[h];
            const bool resc = mx > mo + 8.f;
            const float mn = resc ? mx : mo;
            float p[8];
            #pragma unroll
            for (int r = 0; r < 4; ++r) {
                p[r]     = __expf(slo[r] - mn);
                p[4 + r] = __expf(shi[r] - mn);
            }
            const float sum = ((p[0] + p[1]) + (p[2] + p[3])) +
                              ((p[4] + p[5]) + (p[6] + p[7]));
            float al = 1.f;
            if (resc) { al = __expf(mo - mx); m_i[h] = mx; }
            l_p[h] = l_p[h] * al + sum;
            if (__any(resc)) {
                #pragma unroll
                for (int ci = 0; ci < 16; ++ci) acc[ci][h] *= al;
            }
            const int nn = h * 16 + l15;
            u32x2 wlo, whi;
            wlo[0] = pack2(p[0], p[1]); wlo[1] = pack2(p[2], p[3]);
            whi[0] = pack2(p[4], p[5]); whi[1] = pack2(p[6], p[7]);
            *(u32x2*)&pb[w][nn][q * 4]      = wlo;
            *(u32x2*)&pb[w][nn][16 + q * 4] = whi;
        }

        short8 pB0 = *(const short8*)&pb[w][l15][q * 8];
        short8 pB1 = *(const short8*)&pb[w][16 + l15][q * 8];

        #pragma unroll
        for (int ci = 0; ci < 16; ++ci) {
            short8 vA = *(const short8*)&vs[ci * 16 + l15][q * 8];
            acc[ci][0] = __builtin_amdgcn_mfma_f32_16x16x32_bf16(vA, pB0, acc[ci][0], 0, 0, 0);
            acc[ci][1] = __builtin_amdgcn_mfma_f32_16x16x32_bf16(vA, pB1, acc[ci][1], 0, 0, 0);
        }

        __syncthreads();
        if (more) {
            if (tid < 128) *(short8*)&ks[srow][sseg * 8] = kreg;
            #pragma unroll
            for (int i = 0; i < 4; ++i) *(short8*)&vs[srow + i * 64][sseg * 8] = vreg[i];
        }
        __syncthreads();
    }

    float lfull[2], linv[2];
    #pragma unroll
    for (int h = 0; h < 2; ++h) {
        float l = l_p[h];
        l += __shfl_xor(l, 16);
        l += __shfl_xor(l, 32);
        lfull[h] = l; linv[h] = 1.f / l;
    }
    if (q == 0) {
        #pragma unroll
        for (int h = 0; h < 2; ++h) {
            const size_t idx = (size_t)(g * BB + b) * NN + n0w + h * 16 + l15;
            Mp[idx] = m_i[h];
            Lp[idx] = lfull[h];
        }
    }
    ushort* ob = Op + (size_t)(g * BB + b) * CC * NN;
    #pragma unroll
    for (int ci = 0; ci < 16; ++ci)
        #pragma unroll
        for (int h = 0; h < 2; ++h)
            #pragma unroll
            for (int r = 0; r < 4; ++r)
                ob[(size_t)(ci * 16 + q * 4 + r) * NN + n0w + h * 16 + l15] =
                    f2bf(acc[ci][h][r] * linv[h]);
}

// ---------------- k3: combine, vectorized ----------------
// 1 thread = 8 consecutive n of one (b,c) row. 2048 blocks x 256 threads.
template<int G>
__global__ __launch_bounds__(256) void combine_kernel(
    const ushort* __restrict__ Op, const float* __restrict__ Mp,
    const float* __restrict__ Lp, const float* __restrict__ x,
    const float* __restrict__ gamma, float* __restrict__ out)
{
    const int gid = blockIdx.x * 256 + threadIdx.x;   // 0 .. B*C*(N/8)-1
    const int grp   = gid & (NN / 8 - 1);             // 0..511
    const int rowid = gid >> 9;                       // b*CC + c
    const int b = rowid >> 8;
    const int c = rowid & (CC - 1);
    const int n0 = grp * 8;

    // per-n combine weights from Mp/Lp (L2-resident)
    f32x4 mp[G][2], lp[G][2];
    #pragma unroll
    for (int g = 0; g < G; ++g) {
        const size_t base = (size_t)(g * BB + b) * NN + n0;
        mp[g][0] = *(const f32x4*)&Mp[base];
        mp[g][1] = *(const f32x4*)&Mp[base + 4];
        lp[g][0] = *(const f32x4*)&Lp[base];
        lp[g][1] = *(const f32x4*)&Lp[base + 4];
    }
    float wgt[G][8];
    #pragma unroll
    for (int h = 0; h < 2; ++h) {
        #pragma unroll
        for (int j = 0; j < 4; ++j) {
            float M = -3.0e38f;
            #pragma unroll
            for (int g = 0; g < G; ++g) M = fmaxf(M, mp[g][h][j]);
            float ws = 0.f;
            #pragma unroll
            for (int g = 0; g < G; ++g) {
                const float wv = lp[g][h][j] * __expf(mp[g][h][j] - M);
                wgt[g][h * 4 + j] = wv;
                ws += wv;
            }
            const float inv = 1.f / ws;
            #pragma unroll
            for (int g = 0; g < G; ++g) wgt[g][h * 4 + j] *= inv;
        }
    }

    // combine Op segments
    short8 opv[G];
    #pragma unroll
    for (int g = 0; g < G; ++g)
        opv[g] = *(const short8*)&Op[((size_t)(g * BB + b) * CC + c) * NN + n0];

    const size_t xbase = ((size_t)b * CC + c) * NN + n0;
    const f32x4 x0 = *(const f32x4*)&x[xbase];
    const f32x4 x1 = *(const f32x4*)&x[xbase + 4];
    const float gm = gamma[0];

    f32x4 o0, o1;
    #pragma unroll
    for (int j = 0; j < 4; ++j) {
        float a = 0.f, bsum = 0.f;
        #pragma unroll
        for (int g = 0; g < G; ++g) {
            a    += wgt[g][j]     * bf2f((ushort)opv[g][j]);
            bsum += wgt[g][4 + j] * bf2f((ushort)opv[g][4 + j]);
        }
        o0[j] = gm * a + x0[j];
        o1[j] = gm * bsum + x1[j];
    }
    *(f32x4*)&out[xbase]     = o0;
    *(f32x4*)&out[xbase + 4] = o1;
}

extern "C" void kernel_launch(void* const* d_in, const int* in_sizes, int n_in,
                              void* d_out, int out_size, void* d_ws, size_t ws_size,
                              hipStream_t stream) {
    const float* x     = (const float*)d_in[0];
    const float* Wq    = (const float*)d_in[1];
    const float* bq    = (const float*)d_in[2];
    const float* Wk    = (const float*)d_in[3];
    const float* bk    = (const float*)d_in[4];
    const float* Wv    = (const float*)d_in[5];
    const float* bv    = (const float*)d_in[6];
    const float* gamma = (const float*)d_in[7];
    float* out = (float*)d_out;

    char* p = (char*)d_ws;
    ushort* Wb   = (ushort*)(p);                 // 163840
    float*  bias = (float*) (p + 163840);        // 1280  -> 165120
    ushort* xT   = (ushort*)(p + 165120);        // 8388608 -> 8553728
    ushort* Qb   = (ushort*)(p + 8553728);       // 1048576 -> 9602304
    ushort* Kb   = (ushort*)(p + 9602304);       // 1048576 -> 10650880
    ushort* Vc   = (ushort*)(p + 10650880);      // 8388608 -> 19039488
    float*  Mpb  = (float*) (p + 19039488);      // 262144  -> 19301632
    float*  Lpb  = (float*) (p + 19301632);      // 262144  -> 19563776
    ushort* Opb  = (ushort*)(p + 19563776);      // G*8388608
    // G=4 total: 53,118,208 B; G=2 total: 36,340,992 B
    const int G = (ws_size >= (size_t)53118208) ? 4 : 2;

    pack_w_kernel<<<dim3(320), 256, 0, stream>>>(Wq, bq, Wk, bk, Wv, bv, Wb, bias);
    xpose_kernel<<<dim3(NN / 32, CC / 32, BB), 256, 0, stream>>>(x, xT);
    qkv_mfma_kernel<<<dim3(NN / 64, BB), 256, 0, stream>>>(Wb, bias, xT, Qb, Kb, Vc);
    attn_mfma_kernel<<<dim3(128 * G), 256, 0, stream>>>(Qb, Kb, Vc, Opb, Mpb, Lpb, G, NN / G);
    const int cblocks = BB * CC * (NN / 8) / 256;   // 2048
    if (G == 4)
        combine_kernel<4><<<dim3(cblocks), 256, 0, stream>>>(Opb, Mpb, Lpb, x, gamma, out);
    else
        combine_kernel<2><<<dim3(cblocks), 256, 0, stream>>>(Opb, Mpb, Lpb, x, gamma, out);
}

// Round 7
// 99.143 us; speedup vs baseline: 2.8623x; 1.0330x over previous
//
#include <hip/hip_runtime.h>
#include <math.h>

// PAM module on MFMA, v7: B=4, C=256, H=W=64 -> N=4096, CK=32.
// k2 rebuilt on mfma_f32_32x32x16_bf16:
//   - swapped S^T = K*Q^T: lane owns one n (col=l31), 16 m-slots in regs
//   - k-permuted PV: B-operand (P^T) is the lane's own packed bf16 regs
//     (slot(h2,j) -> m = 16kh + 8(j>>2) + 4h2 + (j&3), applied to V reads too)
//   - LDS holds ONLY V (double-buffered) -> 1 barrier/tile
//   - K/Q direct-global register fragments (L2-hot), T14 early-issue staging
//   - defer-max THR=8, per-lane alpha (col = l31), T5 setprio around PV

#define BB 4
#define CC 256
#define NN 4096
#define CKK 32

typedef __attribute__((ext_vector_type(4))) float f32x4;
typedef __attribute__((ext_vector_type(16))) float f32x16;
typedef __attribute__((ext_vector_type(8))) short short8;
typedef __attribute__((ext_vector_type(4))) short short4v;

static __device__ __forceinline__ ushort f2bf(float f) {
    union { float f; unsigned u; } v; v.f = f;
    unsigned r = v.u + 0x7FFFu + ((v.u >> 16) & 1u);
    return (ushort)(r >> 16);
}
static __device__ __forceinline__ float bf2f(ushort h) {
    union { unsigned u; float f; } v; v.u = ((unsigned)h) << 16;
    return v.f;
}
static __device__ __forceinline__ unsigned pack2(float lo, float hi) {
    return ((unsigned)f2bf(hi) << 16) | (unsigned)f2bf(lo);
}

// ---------------- k0a: pack weights + biases to bf16 ----------------
__global__ __launch_bounds__(256) void pack_w_kernel(
    const float* __restrict__ Wq, const float* __restrict__ bq,
    const float* __restrict__ Wk, const float* __restrict__ bk,
    const float* __restrict__ Wv, const float* __restrict__ bv,
    ushort* __restrict__ Wb, float* __restrict__ bias)
{
    const int o = blockIdx.x;      // 0..319
    const int c = threadIdx.x;     // 0..255
    const float* src; float bsc;
    if (o < 32)      { src = Wq + o * CC;        bsc = bq[o]; }
    else if (o < 64) { src = Wk + (o - 32) * CC; bsc = bk[o - 32]; }
    else             { src = Wv + (o - 64) * CC; bsc = bv[o - 64]; }
    Wb[o * CC + c] = f2bf(src[c]);
    if (c == 0) bias[o] = bsc;
}

// ---------------- k0b: x[b][c][n] fp32 -> xT[b][n][c] bf16 ----------------
__global__ __launch_bounds__(256) void xpose_kernel(
    const float* __restrict__ x, ushort* __restrict__ xT)
{
    __shared__ float t[32][33];
    const int b = blockIdx.z, c0 = blockIdx.y * 32, n0 = blockIdx.x * 32;
    const int tid = threadIdx.x;
    #pragma unroll
    for (int i = 0; i < 4; ++i) {
        int idx = tid + i * 256, rr = idx >> 5, nn = idx & 31;
        t[rr][nn] = x[((size_t)b * CC + c0 + rr) * NN + n0 + nn];
    }
    __syncthreads();
    #pragma unroll
    for (int i = 0; i < 4; ++i) {
        int idx = tid + i * 256, rr = idx >> 5, cc = idx & 31;
        xT[((size_t)b * NN + n0 + rr) * CC + c0 + cc] = f2bf(t[cc][rr]);
    }
}

// ---------------- k1: QKV projections via MFMA ----------------
__global__ __launch_bounds__(256) void qkv_mfma_kernel(
    const ushort* __restrict__ Wb, const float* __restrict__ bias,
    const ushort* __restrict__ xT,
    ushort* __restrict__ Q, ushort* __restrict__ Kt, ushort* __restrict__ V)
{
    const int b = blockIdx.y, n0 = blockIdx.x * 64;
    const int tid = threadIdx.x;
    const int w = tid >> 6, lane = tid & 63, l15 = lane & 15, q = lane >> 4;

    f32x4 acc[5][4];
    #pragma unroll
    for (int c5 = 0; c5 < 5; ++c5)
        #pragma unroll
        for (int nc = 0; nc < 4; ++nc) acc[c5][nc] = (f32x4)0.f;

    #pragma unroll
    for (int ks = 0; ks < 8; ++ks) {
        short8 af[5], bf[4];
        #pragma unroll
        for (int c5 = 0; c5 < 5; ++c5)
            af[c5] = *(const short8*)&Wb[(w * 80 + c5 * 16 + l15) * CC + ks * 32 + q * 8];
        #pragma unroll
        for (int nc = 0; nc < 4; ++nc)
            bf[nc] = *(const short8*)&xT[((size_t)b * NN + n0 + nc * 16 + l15) * CC + ks * 32 + q * 8];
        #pragma unroll
        for (int c5 = 0; c5 < 5; ++c5)
            #pragma unroll
            for (int nc = 0; nc < 4; ++nc)
                acc[c5][nc] = __builtin_amdgcn_mfma_f32_16x16x32_bf16(af[c5], bf[nc], acc[c5][nc], 0, 0, 0);
    }

    #pragma unroll
    for (int c5 = 0; c5 < 5; ++c5) {
        const int o0 = w * 80 + c5 * 16;
        float bia[4];
        #pragma unroll
        for (int r = 0; r < 4; ++r) bia[r] = bias[o0 + q * 4 + r];
        if (o0 >= 64) {
            #pragma unroll
            for (int nc = 0; nc < 4; ++nc)
                #pragma unroll
                for (int r = 0; r < 4; ++r)
                    V[((size_t)b * CC + o0 - 64 + q * 4 + r) * NN + n0 + nc * 16 + l15] =
                        f2bf(acc[c5][nc][r] + bia[r]);
        } else {
            ushort* dst = (o0 < 32) ? Q : Kt;
            const int oo = (o0 & 31) + q * 4;
            #pragma unroll
            for (int nc = 0; nc < 4; ++nc) {
                short4v h;
                #pragma unroll
                for (int r = 0; r < 4; ++r) h[r] = (short)f2bf(acc[c5][nc][r] + bia[r]);
                *(short4v*)&dst[((size_t)b * NN + n0 + nc * 16 + l15) * CKK + oo] = h;
            }
        }
    }
}

// ---------------- k2: flash attention v7 (32x32 MFMA, LDS = V only) ----------
__global__ __launch_bounds__(256, 2) void attn_mfma_kernel(
    const ushort* __restrict__ Q, const ushort* __restrict__ K,
    const ushort* __restrict__ V,
    ushort* __restrict__ Op, float* __restrict__ Mp, float* __restrict__ Lp,
    int G, int NSEG)
{
    __shared__ __align__(16) ushort vs[2][256][40];   // V tile [c][m], 80B rows

    const int id = blockIdx.x;
    const int xcd = id & 7, ix = id >> 3;
    const int b = xcd >> 1;
    int g, row;
    if (G == 4) { g = ((xcd & 1) << 1) | (ix & 1); row = ix >> 1; }
    else        { g = xcd & 1;                     row = ix; }
    const int n0 = row * 128;

    const int tid = threadIdx.x;
    const int w = tid >> 6, lane = tid & 63;
    const int l31 = lane & 31, h2 = lane >> 5;
    const int n0w = n0 + w * 32;          // wave owns 32 n; lane owns n = n0w + l31

    // Q B-frags (col=l31 -> n, k = h2*8+j within each 16-k half), persistent
    const size_t qrow = ((size_t)b * NN + n0w + l31) * CKK;
    short8 qB0 = *(const short8*)&Q[qrow + h2 * 8];
    short8 qB1 = *(const short8*)&Q[qrow + 16 + h2 * 8];

    f32x16 acc[8];                         // O^T: D[c = cb*32 + rowmap(reg,h2)][n=l31]
    #pragma unroll
    for (int cb = 0; cb < 8; ++cb) acc[cb] = (f32x16)0.f;
    float m_i = -3.0e38f, l_p = 0.f;

    const size_t kgb = (size_t)b * NN * CKK;
    const size_t vgb = (size_t)b * CC * NN;
    const int m_start = g * NSEG;
    const int NT = NSEG / 32;

    const int srow = tid >> 2, sseg = tid & 3;   // V staging: 256 thr x 4 rows

    // prologue: K frags tile 0 (regs), V tile 0 -> vs[0]
    short8 kA0 = *(const short8*)&K[kgb + (size_t)(m_start + l31) * CKK + h2 * 8];
    short8 kA1 = *(const short8*)&K[kgb + (size_t)(m_start + l31) * CKK + 16 + h2 * 8];
    short8 vreg[4];
    #pragma unroll
    for (int i = 0; i < 4; ++i)
        vreg[i] = *(const short8*)&V[vgb + (size_t)(srow + i * 64) * NN + m_start + sseg * 8];
    #pragma unroll
    for (int i = 0; i < 4; ++i)
        *(short8*)&vs[0][srow + i * 64][sseg * 8] = vreg[i];
    __syncthreads();

    int cur = 0;
    for (int mt = 0; mt < NT; ++mt) {
        const bool more = (mt + 1 < NT);
        const int m0n = more ? m_start + (mt + 1) * 32 : m_start;  // harmless reread on tail

        // ---- S^T = K.Q^T : D[m][n], lane holds 16 m-slots for n=l31 ----
        f32x16 s = __builtin_amdgcn_mfma_f32_32x32x16_bf16(kA0, qB0, (f32x16)0.f, 0, 0, 0);
        s = __builtin_amdgcn_mfma_f32_32x32x16_bf16(kA1, qB1, s, 0, 0, 0);

        // T14: issue next-tile K + V global loads (land under softmax+PV)
        kA0 = *(const short8*)&K[kgb + (size_t)(m0n + l31) * CKK + h2 * 8];
        kA1 = *(const short8*)&K[kgb + (size_t)(m0n + l31) * CKK + 16 + h2 * 8];
        #pragma unroll
        for (int i = 0; i < 4; ++i)
            vreg[i] = *(const short8*)&V[vgb + (size_t)(srow + i * 64) * NN + m0n + sseg * 8];

        // ---- in-register online softmax (n = l31; m split across h2 halves) ----
        float mx01 = fmaxf(s[0], s[1]),   mx23 = fmaxf(s[2], s[3]);
        float mx45 = fmaxf(s[4], s[5]),   mx67 = fmaxf(s[6], s[7]);
        float mx89 = fmaxf(s[8], s[9]),   mxab = fmaxf(s[10], s[11]);
        float mxcd = fmaxf(s[12], s[13]), mxef = fmaxf(s[14], s[15]);
        float mx = fmaxf(fmaxf(fmaxf(mx01, mx23), fmaxf(mx45, mx67)),
                         fmaxf(fmaxf(mx89, mxab), fmaxf(mxcd, mxef)));
        mx = fmaxf(mx, __shfl_xor(mx, 32));          // combine the two m-halves
        const bool resc = mx > m_i + 8.f;            // defer-max THR=8
        const float mn = resc ? mx : m_i;
        const float al = resc ? __expf(m_i - mx) : 1.f;
        float pp[16];
        #pragma unroll
        for (int r = 0; r < 16; ++r) pp[r] = __expf(s[r] - mn);
        float sum = ((pp[0] + pp[1]) + (pp[2] + pp[3])) + ((pp[4] + pp[5]) + (pp[6] + pp[7]))
                  + ((pp[8] + pp[9]) + (pp[10] + pp[11])) + ((pp[12] + pp[13]) + (pp[14] + pp[15]));
        l_p = l_p * al + sum;
        m_i = mn;
        if (__any(resc)) {                           // alpha per-lane exact (col n = l31)
            #pragma unroll
            for (int cb = 0; cb < 8; ++cb) acc[cb] *= al;
        }

        // pack P to bf16: reg r <-> m = (r&3) + 8*(r>>2) + 4*h2
        union { unsigned u[8]; short8 v[2]; } P;
        #pragma unroll
        for (int g2 = 0; g2 < 8; ++g2) P.u[g2] = pack2(pp[2 * g2], pp[2 * g2 + 1]);
        // B-frag(kh) = own regs 8kh..8kh+7 under k-perm slot(h2,j)->m=16kh+8(j>>2)+4h2+(j&3)

        // ---- PV: acc[c][n] += V[c][m]*P^T[m][n], A reads use the SAME k-perm ----
        __builtin_amdgcn_s_setprio(1);
        #pragma unroll
        for (int cb = 0; cb < 8; ++cb) {
            const ushort* vrow = &vs[cur][cb * 32 + l31][0];
            union { short4v h[2]; short8 v; } A0, A1;
            A0.h[0] = *(const short4v*)&vrow[h2 * 4];          // m = 4h2+0..3
            A0.h[1] = *(const short4v*)&vrow[8 + h2 * 4];      // m = 8+4h2+0..3
            A1.h[0] = *(const short4v*)&vrow[16 + h2 * 4];     // m = 16+4h2+0..3
            A1.h[1] = *(const short4v*)&vrow[24 + h2 * 4];     // m = 24+4h2+0..3
            acc[cb] = __builtin_amdgcn_mfma_f32_32x32x16_bf16(A0.v, P.v[0], acc[cb], 0, 0, 0);
            acc[cb] = __builtin_amdgcn_mfma_f32_32x32x16_bf16(A1.v, P.v[1], acc[cb], 0, 0, 0);
        }
        __builtin_amdgcn_s_setprio(0);

        // ---- stage next V tile into the other buffer; ONE barrier/tile ----
        #pragma unroll
        for (int i = 0; i < 4; ++i)
            *(short8*)&vs[cur ^ 1][srow + i * 64][sseg * 8] = vreg[i];
        __syncthreads();
        cur ^= 1;
    }

    // ---- epilogue ----
    float l = l_p + __shfl_xor(l_p, 32);
    const float linv = 1.f / l;
    if (h2 == 0) {
        const size_t idx = (size_t)(g * BB + b) * NN + n0w + l31;
        Mp[idx] = m_i;
        Lp[idx] = l;
    }
    ushort* ob = Op + (size_t)(g * BB + b) * CC * NN;
    #pragma unroll
    for (int cb = 0; cb < 8; ++cb)
        #pragma unroll
        for (int r = 0; r < 16; ++r) {
            const int c = cb * 32 + (r & 3) + 8 * (r >> 2) + 4 * h2;
            ob[(size_t)c * NN + n0w + l31] = f2bf(acc[cb][r] * linv);
        }
}

// ---------------- k3: combine, vectorized ----------------
template<int G>
__global__ __launch_bounds__(256) void combine_kernel(
    const ushort* __restrict__ Op, const float* __restrict__ Mp,
    const float* __restrict__ Lp, const float* __restrict__ x,
    const float* __restrict__ gamma, float* __restrict__ out)
{
    const int gid = blockIdx.x * 256 + threadIdx.x;   // 0 .. B*C*(N/8)-1
    const int grp   = gid & (NN / 8 - 1);             // 0..511
    const int rowid = gid >> 9;                       // b*CC + c
    const int b = rowid >> 8;
    const int c = rowid & (CC - 1);
    const int n0 = grp * 8;

    f32x4 mp[G][2], lp[G][2];
    #pragma unroll
    for (int g = 0; g < G; ++g) {
        const size_t base = (size_t)(g * BB + b) * NN + n0;
        mp[g][0] = *(const f32x4*)&Mp[base];
        mp[g][1] = *(const f32x4*)&Mp[base + 4];
        lp[g][0] = *(const f32x4*)&Lp[base];
        lp[g][1] = *(const f32x4*)&Lp[base + 4];
    }
    float wgt[G][8];
    #pragma unroll
    for (int h = 0; h < 2; ++h) {
        #pragma unroll
        for (int j = 0; j < 4; ++j) {
            float M = -3.0e38f;
            #pragma unroll
            for (int g = 0; g < G; ++g) M = fmaxf(M, mp[g][h][j]);
            float ws = 0.f;
            #pragma unroll
            for (int g = 0; g < G; ++g) {
                const float wv = lp[g][h][j] * __expf(mp[g][h][j] - M);
                wgt[g][h * 4 + j] = wv;
                ws += wv;
            }
            const float inv = 1.f / ws;
            #pragma unroll
            for (int g = 0; g < G; ++g) wgt[g][h * 4 + j] *= inv;
        }
    }

    short8 opv[G];
    #pragma unroll
    for (int g = 0; g < G; ++g)
        opv[g] = *(const short8*)&Op[((size_t)(g * BB + b) * CC + c) * NN + n0];

    const size_t xbase = ((size_t)b * CC + c) * NN + n0;
    const f32x4 x0 = *(const f32x4*)&x[xbase];
    const f32x4 x1 = *(const f32x4*)&x[xbase + 4];
    const float gm = gamma[0];

    f32x4 o0, o1;
    #pragma unroll
    for (int j = 0; j < 4; ++j) {
        float a = 0.f, bsum = 0.f;
        #pragma unroll
        for (int g = 0; g < G; ++g) {
            a    += wgt[g][j]     * bf2f((ushort)opv[g][j]);
            bsum += wgt[g][4 + j] * bf2f((ushort)opv[g][4 + j]);
        }
        o0[j] = gm * a + x0[j];
        o1[j] = gm * bsum + x1[j];
    }
    *(f32x4*)&out[xbase]     = o0;
    *(f32x4*)&out[xbase + 4] = o1;
}

extern "C" void kernel_launch(void* const* d_in, const int* in_sizes, int n_in,
                              void* d_out, int out_size, void* d_ws, size_t ws_size,
                              hipStream_t stream) {
    const float* x     = (const float*)d_in[0];
    const float* Wq    = (const float*)d_in[1];
    const float* bq    = (const float*)d_in[2];
    const float* Wk    = (const float*)d_in[3];
    const float* bk    = (const float*)d_in[4];
    const float* Wv    = (const float*)d_in[5];
    const float* bv    = (const float*)d_in[6];
    const float* gamma = (const float*)d_in[7];
    float* out = (float*)d_out;

    char* p = (char*)d_ws;
    ushort* Wb   = (ushort*)(p);                 // 163840
    float*  bias = (float*) (p + 163840);        // 1280  -> 165120
    ushort* xT   = (ushort*)(p + 165120);        // 8388608 -> 8553728
    ushort* Qb   = (ushort*)(p + 8553728);       // 1048576 -> 9602304
    ushort* Kb   = (ushort*)(p + 9602304);       // 1048576 -> 10650880
    ushort* Vc   = (ushort*)(p + 10650880);      // 8388608 -> 19039488
    float*  Mpb  = (float*) (p + 19039488);      // 262144  -> 19301632
    float*  Lpb  = (float*) (p + 19301632);      // 262144  -> 19563776
    ushort* Opb  = (ushort*)(p + 19563776);      // G*8388608
    // G=4 total: 53,118,208 B; G=2 total: 36,340,992 B
    const int G = (ws_size >= (size_t)53118208) ? 4 : 2;

    pack_w_kernel<<<dim3(320), 256, 0, stream>>>(Wq, bq, Wk, bk, Wv, bv, Wb, bias);
    xpose_kernel<<<dim3(NN / 32, CC / 32, BB), 256, 0, stream>>>(x, xT);
    qkv_mfma_kernel<<<dim3(NN / 64, BB), 256, 0, stream>>>(Wb, bias, xT, Qb, Kb, Vc);
    attn_mfma_kernel<<<dim3(128 * G), 256, 0, stream>>>(Qb, Kb, Vc, Opb, Mpb, Lpb, G, NN / G);
    const int cblocks = BB * CC * (NN / 8) / 256;   // 2048
    if (G == 4)
        combine_kernel<4><<<dim3(cblocks), 256, 0, stream>>>(Opb, Mpb, Lpb, x, gamma, out);
    else
        combine_kernel<2><<<dim3(cblocks), 256, 0, stream>>>(Opb, Mpb, Lpb, x, gamma, out);
}

// Round 8
// 97.357 us; speedup vs baseline: 2.9148x; 1.0183x over previous
//
#include <hip/hip_runtime.h>
#include <math.h>

// PAM module on MFMA, v8: B=4, C=256, H=W=64 -> N=4096, CK=32.
// v8 changes vs v7 (same operand mappings, mechanical fixes):
//   - V LDS tile in CHUNK-MAJOR XOR layout: vs2[chunk=m/4][c ^ 4*(chunk>>1)]
//     -> conflict-free ds_read_b64 / ds_write_b64 within 16-lane cycle groups
//   - exp2-domain softmax: Q pre-scaled by log2(e) in qkv; v_exp_f32 direct;
//     Mp stored in log2 domain; combine uses exp2
//   - P pack via v_cvt_pk_bf16_f32 (T12 asm recipe)

#define BB 4
#define CC 256
#define NN 4096
#define CKK 32
#define LOG2E 1.44269504f

typedef __attribute__((ext_vector_type(4))) float f32x4;
typedef __attribute__((ext_vector_type(16))) float f32x16;
typedef __attribute__((ext_vector_type(8))) short short8;
typedef __attribute__((ext_vector_type(4))) short short4v;

static __device__ __forceinline__ ushort f2bf(float f) {
    union { float f; unsigned u; } v; v.f = f;
    unsigned r = v.u + 0x7FFFu + ((v.u >> 16) & 1u);
    return (ushort)(r >> 16);
}
static __device__ __forceinline__ float bf2f(ushort h) {
    union { unsigned u; float f; } v; v.u = ((unsigned)h) << 16;
    return v.f;
}
static __device__ __forceinline__ unsigned pack2(float lo, float hi) {
    unsigned r;
    asm("v_cvt_pk_bf16_f32 %0, %1, %2" : "=v"(r) : "v"(lo), "v"(hi));
    return r;
}
static __device__ __forceinline__ float exp2fast(float x) {
    return __builtin_amdgcn_exp2f(x);   // v_exp_f32
}

// chunk-major XOR LDS addressing (ushort index): chunk in [0,8), c in [0,256)
#define VSEL(chunk, c) (((chunk) * 1024) + ((((c) ^ (((chunk) >> 1) << 2))) << 2))

// ---------------- k0a: pack weights + biases to bf16 ----------------
__global__ __launch_bounds__(256) void pack_w_kernel(
    const float* __restrict__ Wq, const float* __restrict__ bq,
    const float* __restrict__ Wk, const float* __restrict__ bk,
    const float* __restrict__ Wv, const float* __restrict__ bv,
    ushort* __restrict__ Wb, float* __restrict__ bias)
{
    const int o = blockIdx.x;      // 0..319
    const int c = threadIdx.x;     // 0..255
    const float* src; float bsc;
    if (o < 32)      { src = Wq + o * CC;        bsc = bq[o]; }
    else if (o < 64) { src = Wk + (o - 32) * CC; bsc = bk[o - 32]; }
    else             { src = Wv + (o - 64) * CC; bsc = bv[o - 64]; }
    Wb[o * CC + c] = f2bf(src[c]);
    if (c == 0) bias[o] = bsc;
}

// ---------------- k0b: x[b][c][n] fp32 -> xT[b][n][c] bf16 ----------------
__global__ __launch_bounds__(256) void xpose_kernel(
    const float* __restrict__ x, ushort* __restrict__ xT)
{
    __shared__ float t[32][33];
    const int b = blockIdx.z, c0 = blockIdx.y * 32, n0 = blockIdx.x * 32;
    const int tid = threadIdx.x;
    #pragma unroll
    for (int i = 0; i < 4; ++i) {
        int idx = tid + i * 256, rr = idx >> 5, nn = idx & 31;
        t[rr][nn] = x[((size_t)b * CC + c0 + rr) * NN + n0 + nn];
    }
    __syncthreads();
    #pragma unroll
    for (int i = 0; i < 4; ++i) {
        int idx = tid + i * 256, rr = idx >> 5, cc = idx & 31;
        xT[((size_t)b * NN + n0 + rr) * CC + c0 + cc] = f2bf(t[cc][rr]);
    }
}

// ---------------- k1: QKV projections via MFMA ----------------
// Q rows are pre-scaled by log2(e) so attention can use exp2 directly.
__global__ __launch_bounds__(256) void qkv_mfma_kernel(
    const ushort* __restrict__ Wb, const float* __restrict__ bias,
    const ushort* __restrict__ xT,
    ushort* __restrict__ Q, ushort* __restrict__ Kt, ushort* __restrict__ V)
{
    const int b = blockIdx.y, n0 = blockIdx.x * 64;
    const int tid = threadIdx.x;
    const int w = tid >> 6, lane = tid & 63, l15 = lane & 15, q = lane >> 4;

    f32x4 acc[5][4];
    #pragma unroll
    for (int c5 = 0; c5 < 5; ++c5)
        #pragma unroll
        for (int nc = 0; nc < 4; ++nc) acc[c5][nc] = (f32x4)0.f;

    #pragma unroll
    for (int ks = 0; ks < 8; ++ks) {
        short8 af[5], bf[4];
        #pragma unroll
        for (int c5 = 0; c5 < 5; ++c5)
            af[c5] = *(const short8*)&Wb[(w * 80 + c5 * 16 + l15) * CC + ks * 32 + q * 8];
        #pragma unroll
        for (int nc = 0; nc < 4; ++nc)
            bf[nc] = *(const short8*)&xT[((size_t)b * NN + n0 + nc * 16 + l15) * CC + ks * 32 + q * 8];
        #pragma unroll
        for (int c5 = 0; c5 < 5; ++c5)
            #pragma unroll
            for (int nc = 0; nc < 4; ++nc)
                acc[c5][nc] = __builtin_amdgcn_mfma_f32_16x16x32_bf16(af[c5], bf[nc], acc[c5][nc], 0, 0, 0);
    }

    #pragma unroll
    for (int c5 = 0; c5 < 5; ++c5) {
        const int o0 = w * 80 + c5 * 16;
        float bia[4];
        #pragma unroll
        for (int r = 0; r < 4; ++r) bia[r] = bias[o0 + q * 4 + r];
        if (o0 >= 64) {
            #pragma unroll
            for (int nc = 0; nc < 4; ++nc)
                #pragma unroll
                for (int r = 0; r < 4; ++r)
                    V[((size_t)b * CC + o0 - 64 + q * 4 + r) * NN + n0 + nc * 16 + l15] =
                        f2bf(acc[c5][nc][r] + bia[r]);
        } else {
            ushort* dst = (o0 < 32) ? Q : Kt;
            const float sc = (o0 < 32) ? LOG2E : 1.0f;   // exp2-domain Q
            const int oo = (o0 & 31) + q * 4;
            #pragma unroll
            for (int nc = 0; nc < 4; ++nc) {
                short4v h;
                #pragma unroll
                for (int r = 0; r < 4; ++r) h[r] = (short)f2bf((acc[c5][nc][r] + bia[r]) * sc);
                *(short4v*)&dst[((size_t)b * NN + n0 + nc * 16 + l15) * CKK + oo] = h;
            }
        }
    }
}

// ---------------- k2: flash attention v8 (32x32 MFMA, chunk-XOR LDS) -------
__global__ __launch_bounds__(256, 2) void attn_mfma_kernel(
    const ushort* __restrict__ Q, const ushort* __restrict__ K,
    const ushort* __restrict__ V,
    ushort* __restrict__ Op, float* __restrict__ Mp, float* __restrict__ Lp,
    int G, int NSEG)
{
    __shared__ __align__(16) ushort vs2[2][8192];   // chunk-major XOR V tile, 16KB/buf

    const int id = blockIdx.x;
    const int xcd = id & 7, ix = id >> 3;
    const int b = xcd >> 1;
    int g, row;
    if (G == 4) { g = ((xcd & 1) << 1) | (ix & 1); row = ix >> 1; }
    else        { g = xcd & 1;                     row = ix; }
    const int n0 = row * 128;

    const int tid = threadIdx.x;
    const int w = tid >> 6, lane = tid & 63;
    const int l31 = lane & 31, h2 = lane >> 5;
    const int n0w = n0 + w * 32;          // wave owns 32 n; lane owns n = n0w + l31

    // Q B-frags (col=l31 -> n, k = h2*8+j within each 16-k half), persistent
    const size_t qrow = ((size_t)b * NN + n0w + l31) * CKK;
    short8 qB0 = *(const short8*)&Q[qrow + h2 * 8];
    short8 qB1 = *(const short8*)&Q[qrow + 16 + h2 * 8];

    f32x16 acc[8];                         // O^T: D[c = cb*32 + rowmap(reg,h2)][n=l31]
    #pragma unroll
    for (int cb = 0; cb < 8; ++cb) acc[cb] = (f32x16)0.f;
    float m_i = -3.0e38f, l_p = 0.f;       // m in log2 domain

    const size_t kgb = (size_t)b * NN * CKK;
    const size_t vgb = (size_t)b * CC * NN;
    const int m_start = g * NSEG;
    const int NT = NSEG / 32;

    const int srow = tid >> 2, sseg = tid & 3;   // V staging: 256 thr x 4 rows

    // prologue: K frags tile 0 (regs), V tile 0 -> vs2[0]
    short8 kA0 = *(const short8*)&K[kgb + (size_t)(m_start + l31) * CKK + h2 * 8];
    short8 kA1 = *(const short8*)&K[kgb + (size_t)(m_start + l31) * CKK + 16 + h2 * 8];
    union { short8 v; short4v h[2]; } vr[4];
    #pragma unroll
    for (int i = 0; i < 4; ++i)
        vr[i].v = *(const short8*)&V[vgb + (size_t)(srow + i * 64) * NN + m_start + sseg * 8];
    #pragma unroll
    for (int i = 0; i < 4; ++i) {
        const int c = srow + i * 64;
        *(short4v*)&vs2[0][VSEL(2 * sseg,     c)] = vr[i].h[0];
        *(short4v*)&vs2[0][VSEL(2 * sseg + 1, c)] = vr[i].h[1];
    }
    __syncthreads();

    int cur = 0;
    for (int mt = 0; mt < NT; ++mt) {
        const bool more = (mt + 1 < NT);
        const int m0n = more ? m_start + (mt + 1) * 32 : m_start;  // harmless reread on tail

        // ---- S^T = K.Q^T : D[m][n], lane holds 16 m-slots for n=l31 ----
        f32x16 s = __builtin_amdgcn_mfma_f32_32x32x16_bf16(kA0, qB0, (f32x16)0.f, 0, 0, 0);
        s = __builtin_amdgcn_mfma_f32_32x32x16_bf16(kA1, qB1, s, 0, 0, 0);

        // T14: issue next-tile K + V global loads (land under softmax+PV)
        kA0 = *(const short8*)&K[kgb + (size_t)(m0n + l31) * CKK + h2 * 8];
        kA1 = *(const short8*)&K[kgb + (size_t)(m0n + l31) * CKK + 16 + h2 * 8];
        #pragma unroll
        for (int i = 0; i < 4; ++i)
            vr[i].v = *(const short8*)&V[vgb + (size_t)(srow + i * 64) * NN + m0n + sseg * 8];

        // ---- in-register online softmax, log2 domain (n = l31) ----
        float mx = fmaxf(
            fmaxf(fmaxf(fmaxf(s[0], s[1]), fmaxf(s[2], s[3])),
                  fmaxf(fmaxf(s[4], s[5]), fmaxf(s[6], s[7]))),
            fmaxf(fmaxf(fmaxf(s[8], s[9]), fmaxf(s[10], s[11])),
                  fmaxf(fmaxf(s[12], s[13]), fmaxf(s[14], s[15]))));
        mx = fmaxf(mx, __shfl_xor(mx, 32));          // combine the two m-halves
        const bool resc = mx > m_i + 8.f;            // defer-max (log2 domain)
        const float mn = resc ? mx : m_i;
        const float al = resc ? exp2fast(m_i - mx) : 1.f;
        float pp[16];
        #pragma unroll
        for (int r = 0; r < 16; ++r) pp[r] = exp2fast(s[r] - mn);
        float sum = ((pp[0] + pp[1]) + (pp[2] + pp[3])) + ((pp[4] + pp[5]) + (pp[6] + pp[7]))
                  + ((pp[8] + pp[9]) + (pp[10] + pp[11])) + ((pp[12] + pp[13]) + (pp[14] + pp[15]));
        l_p = l_p * al + sum;
        m_i = mn;
        if (__any(resc)) {                           // alpha per-lane exact (col n = l31)
            #pragma unroll
            for (int cb = 0; cb < 8; ++cb) acc[cb] *= al;
        }

        // pack P to bf16: reg r <-> m = (r&3) + 8*(r>>2) + 4*h2
        union { unsigned u[8]; short8 v[2]; } P;
        #pragma unroll
        for (int g2 = 0; g2 < 8; ++g2) P.u[g2] = pack2(pp[2 * g2], pp[2 * g2 + 1]);

        // ---- PV: acc[c][n] += V[c][m]*P^T[m][n], A reads use the SAME k-perm ----
        __builtin_amdgcn_s_setprio(1);
        #pragma unroll
        for (int cb = 0; cb < 8; ++cb) {
            const int c = cb * 32 + l31;
            union { short4v h[2]; short8 v; } A0, A1;
            A0.h[0] = *(const short4v*)&vs2[cur][VSEL(h2,     c)];   // m = 4h2+0..3
            A0.h[1] = *(const short4v*)&vs2[cur][VSEL(2 + h2, c)];   // m = 8+4h2+0..3
            A1.h[0] = *(const short4v*)&vs2[cur][VSEL(4 + h2, c)];   // m = 16+4h2+0..3
            A1.h[1] = *(const short4v*)&vs2[cur][VSEL(6 + h2, c)];   // m = 24+4h2+0..3
            acc[cb] = __builtin_amdgcn_mfma_f32_32x32x16_bf16(A0.v, P.v[0], acc[cb], 0, 0, 0);
            acc[cb] = __builtin_amdgcn_mfma_f32_32x32x16_bf16(A1.v, P.v[1], acc[cb], 0, 0, 0);
        }
        __builtin_amdgcn_s_setprio(0);

        // ---- stage next V tile into the other buffer; ONE barrier/tile ----
        #pragma unroll
        for (int i = 0; i < 4; ++i) {
            const int c = srow + i * 64;
            *(short4v*)&vs2[cur ^ 1][VSEL(2 * sseg,     c)] = vr[i].h[0];
            *(short4v*)&vs2[cur ^ 1][VSEL(2 * sseg + 1, c)] = vr[i].h[1];
        }
        __syncthreads();
        cur ^= 1;
    }

    // ---- epilogue ----
    float l = l_p + __shfl_xor(l_p, 32);
    const float linv = 1.f / l;
    if (h2 == 0) {
        const size_t idx = (size_t)(g * BB + b) * NN + n0w + l31;
        Mp[idx] = m_i;                               // log2 domain
        Lp[idx] = l;
    }
    ushort* ob = Op + (size_t)(g * BB + b) * CC * NN;
    #pragma unroll
    for (int cb = 0; cb < 8; ++cb)
        #pragma unroll
        for (int r = 0; r < 16; ++r) {
            const int c = cb * 32 + (r & 3) + 8 * (r >> 2) + 4 * h2;
            ob[(size_t)c * NN + n0w + l31] = f2bf(acc[cb][r] * linv);
        }
}

// ---------------- k3: combine, vectorized (log2-domain Mp) ----------------
template<int G>
__global__ __launch_bounds__(256) void combine_kernel(
    const ushort* __restrict__ Op, const float* __restrict__ Mp,
    const float* __restrict__ Lp, const float* __restrict__ x,
    const float* __restrict__ gamma, float* __restrict__ out)
{
    const int gid = blockIdx.x * 256 + threadIdx.x;   // 0 .. B*C*(N/8)-1
    const int grp   = gid & (NN / 8 - 1);             // 0..511
    const int rowid = gid >> 9;                       // b*CC + c
    const int b = rowid >> 8;
    const int c = rowid & (CC - 1);
    const int n0 = grp * 8;

    f32x4 mp[G][2], lp[G][2];
    #pragma unroll
    for (int g = 0; g < G; ++g) {
        const size_t base = (size_t)(g * BB + b) * NN + n0;
        mp[g][0] = *(const f32x4*)&Mp[base];
        mp[g][1] = *(const f32x4*)&Mp[base + 4];
        lp[g][0] = *(const f32x4*)&Lp[base];
        lp[g][1] = *(const f32x4*)&Lp[base + 4];
    }
    float wgt[G][8];
    #pragma unroll
    for (int h = 0; h < 2; ++h) {
        #pragma unroll
        for (int j = 0; j < 4; ++j) {
            float M = -3.0e38f;
            #pragma unroll
            for (int g = 0; g < G; ++g) M = fmaxf(M, mp[g][h][j]);
            float ws = 0.f;
            #pragma unroll
            for (int g = 0; g < G; ++g) {
                const float wv = lp[g][h][j] * exp2fast(mp[g][h][j] - M);  // log2 domain
                wgt[g][h * 4 + j] = wv;
                ws += wv;
            }
            const float inv = 1.f / ws;
            #pragma unroll
            for (int g = 0; g < G; ++g) wgt[g][h * 4 + j] *= inv;
        }
    }

    short8 opv[G];
    #pragma unroll
    for (int g = 0; g < G; ++g)
        opv[g] = *(const short8*)&Op[((size_t)(g * BB + b) * CC + c) * NN + n0];

    const size_t xbase = ((size_t)b * CC + c) * NN + n0;
    const f32x4 x0 = *(const f32x4*)&x[xbase];
    const f32x4 x1 = *(const f32x4*)&x[xbase + 4];
    const float gm = gamma[0];

    f32x4 o0, o1;
    #pragma unroll
    for (int j = 0; j < 4; ++j) {
        float a = 0.f, bsum = 0.f;
        #pragma unroll
        for (int g = 0; g < G; ++g) {
            a    += wgt[g][j]     * bf2f((ushort)opv[g][j]);
            bsum += wgt[g][4 + j] * bf2f((ushort)opv[g][4 + j]);
        }
        o0[j] = gm * a + x0[j];
        o1[j] = gm * bsum + x1[j];
    }
    *(f32x4*)&out[xbase]     = o0;
    *(f32x4*)&out[xbase + 4] = o1;
}

extern "C" void kernel_launch(void* const* d_in, const int* in_sizes, int n_in,
                              void* d_out, int out_size, void* d_ws, size_t ws_size,
                              hipStream_t stream) {
    const float* x     = (const float*)d_in[0];
    const float* Wq    = (const float*)d_in[1];
    const float* bq    = (const float*)d_in[2];
    const float* Wk    = (const float*)d_in[3];
    const float* bk    = (const float*)d_in[4];
    const float* Wv    = (const float*)d_in[5];
    const float* bv    = (const float*)d_in[6];
    const float* gamma = (const float*)d_in[7];
    float* out = (float*)d_out;

    char* p = (char*)d_ws;
    ushort* Wb   = (ushort*)(p);                 // 163840
    float*  bias = (float*) (p + 163840);        // 1280  -> 165120
    ushort* xT   = (ushort*)(p + 165120);        // 8388608 -> 8553728
    ushort* Qb   = (ushort*)(p + 8553728);       // 1048576 -> 9602304
    ushort* Kb   = (ushort*)(p + 9602304);       // 1048576 -> 10650880
    ushort* Vc   = (ushort*)(p + 10650880);      // 8388608 -> 19039488
    float*  Mpb  = (float*) (p + 19039488);      // 262144  -> 19301632
    float*  Lpb  = (float*) (p + 19301632);      // 262144  -> 19563776
    ushort* Opb  = (ushort*)(p + 19563776);      // G*8388608
    // G=4 total: 53,118,208 B; G=2 total: 36,340,992 B
    const int G = (ws_size >= (size_t)53118208) ? 4 : 2;

    pack_w_kernel<<<dim3(320), 256, 0, stream>>>(Wq, bq, Wk, bk, Wv, bv, Wb, bias);
    xpose_kernel<<<dim3(NN / 32, CC / 32, BB), 256, 0, stream>>>(x, xT);
    qkv_mfma_kernel<<<dim3(NN / 64, BB), 256, 0, stream>>>(Wb, bias, xT, Qb, Kb, Vc);
    attn_mfma_kernel<<<dim3(128 * G), 256, 0, stream>>>(Qb, Kb, Vc, Opb, Mpb, Lpb, G, NN / G);
    const int cblocks = BB * CC * (NN / 8) / 256;   // 2048
    if (G == 4)
        combine_kernel<4><<<dim3(cblocks), 256, 0, stream>>>(Opb, Mpb, Lpb, x, gamma, out);
    else
        combine_kernel<2><<<dim3(cblocks), 256, 0, stream>>>(Opb, Mpb, Lpb, x, gamma, out);
}

// Round 9
// 97.122 us; speedup vs baseline: 2.9219x; 1.0024x over previous
//
#include <hip/hip_runtime.h>
#include <math.h>

// PAM module on MFMA, v8: B=4, C=256, H=W=64 -> N=4096, CK=32.
// v8 changes vs v7 (same operand mappings, mechanical fixes):
//   - V LDS tile in CHUNK-MAJOR XOR layout: vs2[chunk=m/4][c ^ 4*(chunk>>1)]
//     -> conflict-free ds_read_b64 / ds_write_b64 within 16-lane cycle groups
//   - exp2-domain softmax: Q pre-scaled by log2(e) in qkv; v_exp_f32 direct;
//     Mp stored in log2 domain; combine uses exp2
//   - P pack via v_cvt_pk_bf16_f32 (T12 asm recipe)

#define BB 4
#define CC 256
#define NN 4096
#define CKK 32
#define LOG2E 1.44269504f

typedef __attribute__((ext_vector_type(4))) float f32x4;
typedef __attribute__((ext_vector_type(16))) float f32x16;
typedef __attribute__((ext_vector_type(8))) short short8;
typedef __attribute__((ext_vector_type(4))) short short4v;

static __device__ __forceinline__ ushort f2bf(float f) {
    union { float f; unsigned u; } v; v.f = f;
    unsigned r = v.u + 0x7FFFu + ((v.u >> 16) & 1u);
    return (ushort)(r >> 16);
}
static __device__ __forceinline__ float bf2f(ushort h) {
    union { unsigned u; float f; } v; v.u = ((unsigned)h) << 16;
    return v.f;
}
static __device__ __forceinline__ unsigned pack2(float lo, float hi) {
    unsigned r;
    asm("v_cvt_pk_bf16_f32 %0, %1, %2" : "=v"(r) : "v"(lo), "v"(hi));
    return r;
}
static __device__ __forceinline__ float exp2fast(float x) {
    return __builtin_amdgcn_exp2f(x);   // v_exp_f32
}

// chunk-major XOR LDS addressing (ushort index): chunk in [0,8), c in [0,256)
#define VSEL(chunk, c) (((chunk) * 1024) + ((((c) ^ (((chunk) >> 1) << 2))) << 2))

// ---------------- k0a: pack weights + biases to bf16 ----------------
__global__ __launch_bounds__(256) void pack_w_kernel(
    const float* __restrict__ Wq, const float* __restrict__ bq,
    const float* __restrict__ Wk, const float* __restrict__ bk,
    const float* __restrict__ Wv, const float* __restrict__ bv,
    ushort* __restrict__ Wb, float* __restrict__ bias)
{
    const int o = blockIdx.x;      // 0..319
    const int c = threadIdx.x;     // 0..255
    const float* src; float bsc;
    if (o < 32)      { src = Wq + o * CC;        bsc = bq[o]; }
    else if (o < 64) { src = Wk + (o - 32) * CC; bsc = bk[o - 32]; }
    else             { src = Wv + (o - 64) * CC; bsc = bv[o - 64]; }
    Wb[o * CC + c] = f2bf(src[c]);
    if (c == 0) bias[o] = bsc;
}

// ---------------- k0b: x[b][c][n] fp32 -> xT[b][n][c] bf16 ----------------
__global__ __launch_bounds__(256) void xpose_kernel(
    const float* __restrict__ x, ushort* __restrict__ xT)
{
    __shared__ float t[32][33];
    const int b = blockIdx.z, c0 = blockIdx.y * 32, n0 = blockIdx.x * 32;
    const int tid = threadIdx.x;
    #pragma unroll
    for (int i = 0; i < 4; ++i) {
        int idx = tid + i * 256, rr = idx >> 5, nn = idx & 31;
        t[rr][nn] = x[((size_t)b * CC + c0 + rr) * NN + n0 + nn];
    }
    __syncthreads();
    #pragma unroll
    for (int i = 0; i < 4; ++i) {
        int idx = tid + i * 256, rr = idx >> 5, cc = idx & 31;
        xT[((size_t)b * NN + n0 + rr) * CC + c0 + cc] = f2bf(t[cc][rr]);
    }
}

// ---------------- k1: QKV projections via MFMA ----------------
// Q rows are pre-scaled by log2(e) so attention can use exp2 directly.
__global__ __launch_bounds__(256) void qkv_mfma_kernel(
    const ushort* __restrict__ Wb, const float* __restrict__ bias,
    const ushort* __restrict__ xT,
    ushort* __restrict__ Q, ushort* __restrict__ Kt, ushort* __restrict__ V)
{
    const int b = blockIdx.y, n0 = blockIdx.x * 64;
    const int tid = threadIdx.x;
    const int w = tid >> 6, lane = tid & 63, l15 = lane & 15, q = lane >> 4;

    f32x4 acc[5][4];
    #pragma unroll
    for (int c5 = 0; c5 < 5; ++c5)
        #pragma unroll
        for (int nc = 0; nc < 4; ++nc) acc[c5][nc] = (f32x4)0.f;

    #pragma unroll
    for (int ks = 0; ks < 8; ++ks) {
        short8 af[5], bf[4];
        #pragma unroll
        for (int c5 = 0; c5 < 5; ++c5)
            af[c5] = *(const short8*)&Wb[(w * 80 + c5 * 16 + l15) * CC + ks * 32 + q * 8];
        #pragma unroll
        for (int nc = 0; nc < 4; ++nc)
            bf[nc] = *(const short8*)&xT[((size_t)b * NN + n0 + nc * 16 + l15) * CC + ks * 32 + q * 8];
        #pragma unroll
        for (int c5 = 0; c5 < 5; ++c5)
            #pragma unroll
            for (int nc = 0; nc < 4; ++nc)
                acc[c5][nc] = __builtin_amdgcn_mfma_f32_16x16x32_bf16(af[c5], bf[nc], acc[c5][nc], 0, 0, 0);
    }

    #pragma unroll
    for (int c5 = 0; c5 < 5; ++c5) {
        const int o0 = w * 80 + c5 * 16;
        float bia[4];
        #pragma unroll
        for (int r = 0; r < 4; ++r) bia[r] = bias[o0 + q * 4 + r];
        if (o0 >= 64) {
            #pragma unroll
            for (int nc = 0; nc < 4; ++nc)
                #pragma unroll
                for (int r = 0; r < 4; ++r)
                    V[((size_t)b * CC + o0 - 64 + q * 4 + r) * NN + n0 + nc * 16 + l15] =
                        f2bf(acc[c5][nc][r] + bia[r]);
        } else {
            ushort* dst = (o0 < 32) ? Q : Kt;
            const float sc = (o0 < 32) ? LOG2E : 1.0f;   // exp2-domain Q
            const int oo = (o0 & 31) + q * 4;
            #pragma unroll
            for (int nc = 0; nc < 4; ++nc) {
                short4v h;
                #pragma unroll
                for (int r = 0; r < 4; ++r) h[r] = (short)f2bf((acc[c5][nc][r] + bia[r]) * sc);
                *(short4v*)&dst[((size_t)b * NN + n0 + nc * 16 + l15) * CKK + oo] = h;
            }
        }
    }
}

// ---------------- k2: flash attention v8 (32x32 MFMA, chunk-XOR LDS) -------
__global__ __launch_bounds__(256, 2) void attn_mfma_kernel(
    const ushort* __restrict__ Q, const ushort* __restrict__ K,
    const ushort* __restrict__ V,
    ushort* __restrict__ Op, float* __restrict__ Mp, float* __restrict__ Lp,
    int G, int NSEG)
{
    __shared__ __align__(16) ushort vs2[2][8192];   // chunk-major XOR V tile, 16KB/buf

    const int id = blockIdx.x;
    const int xcd = id & 7, ix = id >> 3;
    const int b = xcd >> 1;
    int g, row;
    if (G == 4) { g = ((xcd & 1) << 1) | (ix & 1); row = ix >> 1; }
    else        { g = xcd & 1;                     row = ix; }
    const int n0 = row * 128;

    const int tid = threadIdx.x;
    const int w = tid >> 6, lane = tid & 63;
    const int l31 = lane & 31, h2 = lane >> 5;
    const int n0w = n0 + w * 32;          // wave owns 32 n; lane owns n = n0w + l31

    // Q B-frags (col=l31 -> n, k = h2*8+j within each 16-k half), persistent
    const size_t qrow = ((size_t)b * NN + n0w + l31) * CKK;
    short8 qB0 = *(const short8*)&Q[qrow + h2 * 8];
    short8 qB1 = *(const short8*)&Q[qrow + 16 + h2 * 8];

    f32x16 acc[8];                         // O^T: D[c = cb*32 + rowmap(reg,h2)][n=l31]
    #pragma unroll
    for (int cb = 0; cb < 8; ++cb) acc[cb] = (f32x16)0.f;
    float m_i = -3.0e38f, l_p = 0.f;       // m in log2 domain

    const size_t kgb = (size_t)b * NN * CKK;
    const size_t vgb = (size_t)b * CC * NN;
    const int m_start = g * NSEG;
    const int NT = NSEG / 32;

    const int srow = tid >> 2, sseg = tid & 3;   // V staging: 256 thr x 4 rows

    // prologue: K frags tile 0 (regs), V tile 0 -> vs2[0]
    short8 kA0 = *(const short8*)&K[kgb + (size_t)(m_start + l31) * CKK + h2 * 8];
    short8 kA1 = *(const short8*)&K[kgb + (size_t)(m_start + l31) * CKK + 16 + h2 * 8];
    union { short8 v; short4v h[2]; } vr[4];
    #pragma unroll
    for (int i = 0; i < 4; ++i)
        vr[i].v = *(const short8*)&V[vgb + (size_t)(srow + i * 64) * NN + m_start + sseg * 8];
    #pragma unroll
    for (int i = 0; i < 4; ++i) {
        const int c = srow + i * 64;
        *(short4v*)&vs2[0][VSEL(2 * sseg,     c)] = vr[i].h[0];
        *(short4v*)&vs2[0][VSEL(2 * sseg + 1, c)] = vr[i].h[1];
    }
    __syncthreads();

    int cur = 0;
    for (int mt = 0; mt < NT; ++mt) {
        const bool more = (mt + 1 < NT);
        const int m0n = more ? m_start + (mt + 1) * 32 : m_start;  // harmless reread on tail

        // ---- S^T = K.Q^T : D[m][n], lane holds 16 m-slots for n=l31 ----
        f32x16 s = __builtin_amdgcn_mfma_f32_32x32x16_bf16(kA0, qB0, (f32x16)0.f, 0, 0, 0);
        s = __builtin_amdgcn_mfma_f32_32x32x16_bf16(kA1, qB1, s, 0, 0, 0);

        // T14: issue next-tile K + V global loads (land under softmax+PV)
        kA0 = *(const short8*)&K[kgb + (size_t)(m0n + l31) * CKK + h2 * 8];
        kA1 = *(const short8*)&K[kgb + (size_t)(m0n + l31) * CKK + 16 + h2 * 8];
        #pragma unroll
        for (int i = 0; i < 4; ++i)
            vr[i].v = *(const short8*)&V[vgb + (size_t)(srow + i * 64) * NN + m0n + sseg * 8];

        // ---- in-register online softmax, log2 domain (n = l31) ----
        float mx = fmaxf(
            fmaxf(fmaxf(fmaxf(s[0], s[1]), fmaxf(s[2], s[3])),
                  fmaxf(fmaxf(s[4], s[5]), fmaxf(s[6], s[7]))),
            fmaxf(fmaxf(fmaxf(s[8], s[9]), fmaxf(s[10], s[11])),
                  fmaxf(fmaxf(s[12], s[13]), fmaxf(s[14], s[15]))));
        mx = fmaxf(mx, __shfl_xor(mx, 32));          // combine the two m-halves
        const bool resc = mx > m_i + 8.f;            // defer-max (log2 domain)
        const float mn = resc ? mx : m_i;
        const float al = resc ? exp2fast(m_i - mx) : 1.f;
        float pp[16];
        #pragma unroll
        for (int r = 0; r < 16; ++r) pp[r] = exp2fast(s[r] - mn);
        float sum = ((pp[0] + pp[1]) + (pp[2] + pp[3])) + ((pp[4] + pp[5]) + (pp[6] + pp[7]))
                  + ((pp[8] + pp[9]) + (pp[10] + pp[11])) + ((pp[12] + pp[13]) + (pp[14] + pp[15]));
        l_p = l_p * al + sum;
        m_i = mn;
        if (__any(resc)) {                           // alpha per-lane exact (col n = l31)
            #pragma unroll
            for (int cb = 0; cb < 8; ++cb) acc[cb] *= al;
        }

        // pack P to bf16: reg r <-> m = (r&3) + 8*(r>>2) + 4*h2
        union { unsigned u[8]; short8 v[2]; } P;
        #pragma unroll
        for (int g2 = 0; g2 < 8; ++g2) P.u[g2] = pack2(pp[2 * g2], pp[2 * g2 + 1]);

        // ---- PV: acc[c][n] += V[c][m]*P^T[m][n], A reads use the SAME k-perm ----
        __builtin_amdgcn_s_setprio(1);
        #pragma unroll
        for (int cb = 0; cb < 8; ++cb) {
            const int c = cb * 32 + l31;
            union { short4v h[2]; short8 v; } A0, A1;
            A0.h[0] = *(const short4v*)&vs2[cur][VSEL(h2,     c)];   // m = 4h2+0..3
            A0.h[1] = *(const short4v*)&vs2[cur][VSEL(2 + h2, c)];   // m = 8+4h2+0..3
            A1.h[0] = *(const short4v*)&vs2[cur][VSEL(4 + h2, c)];   // m = 16+4h2+0..3
            A1.h[1] = *(const short4v*)&vs2[cur][VSEL(6 + h2, c)];   // m = 24+4h2+0..3
            acc[cb] = __builtin_amdgcn_mfma_f32_32x32x16_bf16(A0.v, P.v[0], acc[cb], 0, 0, 0);
            acc[cb] = __builtin_amdgcn_mfma_f32_32x32x16_bf16(A1.v, P.v[1], acc[cb], 0, 0, 0);
        }
        __builtin_amdgcn_s_setprio(0);

        // ---- stage next V tile into the other buffer; ONE barrier/tile ----
        #pragma unroll
        for (int i = 0; i < 4; ++i) {
            const int c = srow + i * 64;
            *(short4v*)&vs2[cur ^ 1][VSEL(2 * sseg,     c)] = vr[i].h[0];
            *(short4v*)&vs2[cur ^ 1][VSEL(2 * sseg + 1, c)] = vr[i].h[1];
        }
        __syncthreads();
        cur ^= 1;
    }

    // ---- epilogue ----
    float l = l_p + __shfl_xor(l_p, 32);
    const float linv = 1.f / l;
    if (h2 == 0) {
        const size_t idx = (size_t)(g * BB + b) * NN + n0w + l31;
        Mp[idx] = m_i;                               // log2 domain
        Lp[idx] = l;
    }
    ushort* ob = Op + (size_t)(g * BB + b) * CC * NN;
    #pragma unroll
    for (int cb = 0; cb < 8; ++cb)
        #pragma unroll
        for (int r = 0; r < 16; ++r) {
            const int c = cb * 32 + (r & 3) + 8 * (r >> 2) + 4 * h2;
            ob[(size_t)c * NN + n0w + l31] = f2bf(acc[cb][r] * linv);
        }
}

// ---------------- k3: combine, vectorized (log2-domain Mp) ----------------
template<int G>
__global__ __launch_bounds__(256) void combine_kernel(
    const ushort* __restrict__ Op, const float* __restrict__ Mp,
    const float* __restrict__ Lp, const float* __restrict__ x,
    const float* __restrict__ gamma, float* __restrict__ out)
{
    const int gid = blockIdx.x * 256 + threadIdx.x;   // 0 .. B*C*(N/8)-1
    const int grp   = gid & (NN / 8 - 1);             // 0..511
    const int rowid = gid >> 9;                       // b*CC + c
    const int b = rowid >> 8;
    const int c = rowid & (CC - 1);
    const int n0 = grp * 8;

    f32x4 mp[G][2], lp[G][2];
    #pragma unroll
    for (int g = 0; g < G; ++g) {
        const size_t base = (size_t)(g * BB + b) * NN + n0;
        mp[g][0] = *(const f32x4*)&Mp[base];
        mp[g][1] = *(const f32x4*)&Mp[base + 4];
        lp[g][0] = *(const f32x4*)&Lp[base];
        lp[g][1] = *(const f32x4*)&Lp[base + 4];
    }
    float wgt[G][8];
    #pragma unroll
    for (int h = 0; h < 2; ++h) {
        #pragma unroll
        for (int j = 0; j < 4; ++j) {
            float M = -3.0e38f;
            #pragma unroll
            for (int g = 0; g < G; ++g) M = fmaxf(M, mp[g][h][j]);
            float ws = 0.f;
            #pragma unroll
            for (int g = 0; g < G; ++g) {
                const float wv = lp[g][h][j] * exp2fast(mp[g][h][j] - M);  // log2 domain
                wgt[g][h * 4 + j] = wv;
                ws += wv;
            }
            const float inv = 1.f / ws;
            #pragma unroll
            for (int g = 0; g < G; ++g) wgt[g][h * 4 + j] *= inv;
        }
    }

    short8 opv[G];
    #pragma unroll
    for (int g = 0; g < G; ++g)
        opv[g] = *(const short8*)&Op[((size_t)(g * BB + b) * CC + c) * NN + n0];

    const size_t xbase = ((size_t)b * CC + c) * NN + n0;
    const f32x4 x0 = *(const f32x4*)&x[xbase];
    const f32x4 x1 = *(const f32x4*)&x[xbase + 4];
    const float gm = gamma[0];

    f32x4 o0, o1;
    #pragma unroll
    for (int j = 0; j < 4; ++j) {
        float a = 0.f, bsum = 0.f;
        #pragma unroll
        for (int g = 0; g < G; ++g) {
            a    += wgt[g][j]     * bf2f((ushort)opv[g][j]);
            bsum += wgt[g][4 + j] * bf2f((ushort)opv[g][4 + j]);
        }
        o0[j] = gm * a + x0[j];
        o1[j] = gm * bsum + x1[j];
    }
    *(f32x4*)&out[xbase]     = o0;
    *(f32x4*)&out[xbase + 4] = o1;
}

extern "C" void kernel_launch(void* const* d_in, const int* in_sizes, int n_in,
                              void* d_out, int out_size, void* d_ws, size_t ws_size,
                              hipStream_t stream) {
    const float* x     = (const float*)d_in[0];
    const float* Wq    = (const float*)d_in[1];
    const float* bq    = (const float*)d_in[2];
    const float* Wk    = (const float*)d_in[3];
    const float* bk    = (const float*)d_in[4];
    const float* Wv    = (const float*)d_in[5];
    const float* bv    = (const float*)d_in[6];
    const float* gamma = (const float*)d_in[7];
    float* out = (float*)d_out;

    char* p = (char*)d_ws;
    ushort* Wb   = (ushort*)(p);                 // 163840
    float*  bias = (float*) (p + 163840);        // 1280  -> 165120
    ushort* xT   = (ushort*)(p + 165120);        // 8388608 -> 8553728
    ushort* Qb   = (ushort*)(p + 8553728);       // 1048576 -> 9602304
    ushort* Kb   = (ushort*)(p + 9602304);       // 1048576 -> 10650880
    ushort* Vc   = (ushort*)(p + 10650880);      // 8388608 -> 19039488
    float*  Mpb  = (float*) (p + 19039488);      // 262144  -> 19301632
    float*  Lpb  = (float*) (p + 19301632);      // 262144  -> 19563776
    ushort* Opb  = (ushort*)(p + 19563776);      // G*8388608
    // G=4 total: 53,118,208 B; G=2 total: 36,340,992 B
    const int G = (ws_size >= (size_t)53118208) ? 4 : 2;

    pack_w_kernel<<<dim3(320), 256, 0, stream>>>(Wq, bq, Wk, bk, Wv, bv, Wb, bias);
    xpose_kernel<<<dim3(NN / 32, CC / 32, BB), 256, 0, stream>>>(x, xT);
    qkv_mfma_kernel<<<dim3(NN / 64, BB), 256, 0, stream>>>(Wb, bias, xT, Qb, Kb, Vc);
    attn_mfma_kernel<<<dim3(128 * G), 256, 0, stream>>>(Qb, Kb, Vc, Opb, Mpb, Lpb, G, NN / G);
    const int cblocks = BB * CC * (NN / 8) / 256;   // 2048
    if (G == 4)
        combine_kernel<4><<<dim3(cblocks), 256, 0, stream>>>(Opb, Mpb, Lpb, x, gamma, out);
    else
        combine_kernel<2><<<dim3(cblocks), 256, 0, stream>>>(Opb, Mpb, Lpb, x, gamma, out);
}

// Round 10
// 89.335 us; speedup vs baseline: 3.1766x; 1.0872x over previous
//
#include <hip/hip_runtime.h>
#include <math.h>

// PAM module on MFMA, v9: B=4, C=256, H=W=64 -> N=4096, CK=32.
// v9 changes vs v8:
//   - attn: S-pipelining (S_{t+1} computed before softmax_t; MFMA latency
//     hidden under VALU), unit-major V LDS layout vs2[kh2][c][8] whose 16B
//     units ARE the PV A-fragments (b128 contiguous reads, no XOR needed),
//     fused exp+sum+pack (no pp[] array, register-neutral), max3 reduce.
//   - qkv: reads fp32 x directly (coalesced dword B-frags + cvt_pk_bf16),
//     xpose kernel and xT buffer deleted.

#define BB 4
#define CC 256
#define NN 4096
#define CKK 32
#define LOG2E 1.44269504f

typedef __attribute__((ext_vector_type(4))) float f32x4;
typedef __attribute__((ext_vector_type(16))) float f32x16;
typedef __attribute__((ext_vector_type(8))) short short8;
typedef __attribute__((ext_vector_type(4))) short short4v;

static __device__ __forceinline__ ushort f2bf(float f) {
    union { float f; unsigned u; } v; v.f = f;
    unsigned r = v.u + 0x7FFFu + ((v.u >> 16) & 1u);
    return (ushort)(r >> 16);
}
static __device__ __forceinline__ float bf2f(ushort h) {
    union { unsigned u; float f; } v; v.u = ((unsigned)h) << 16;
    return v.f;
}
static __device__ __forceinline__ unsigned pack2(float lo, float hi) {
    unsigned r;
    asm("v_cvt_pk_bf16_f32 %0, %1, %2" : "=v"(r) : "v"(lo), "v"(hi));
    return r;
}
static __device__ __forceinline__ float exp2fast(float x) {
    return __builtin_amdgcn_exp2f(x);   // v_exp_f32
}

// ---------------- k0: pack weights + biases to bf16 ----------------
__global__ __launch_bounds__(256) void pack_w_kernel(
    const float* __restrict__ Wq, const float* __restrict__ bq,
    const float* __restrict__ Wk, const float* __restrict__ bk,
    const float* __restrict__ Wv, const float* __restrict__ bv,
    ushort* __restrict__ Wb, float* __restrict__ bias)
{
    const int o = blockIdx.x;      // 0..319
    const int c = threadIdx.x;     // 0..255
    const float* src; float bsc;
    if (o < 32)      { src = Wq + o * CC;        bsc = bq[o]; }
    else if (o < 64) { src = Wk + (o - 32) * CC; bsc = bk[o - 32]; }
    else             { src = Wv + (o - 64) * CC; bsc = bv[o - 64]; }
    Wb[o * CC + c] = f2bf(src[c]);
    if (c == 0) bias[o] = bsc;
}

// ---------------- k1: QKV projections via MFMA, direct fp32 x reads --------
// B-frag: lane (l15, q) needs x[c = ks*32+q*8+j][n = n0+nc*16+l15], j=0..7.
// For fixed c the 16 lanes read 16 consecutive floats (64B coalesced).
__global__ __launch_bounds__(256) void qkv_mfma_kernel(
    const ushort* __restrict__ Wb, const float* __restrict__ bias,
    const float* __restrict__ x,
    ushort* __restrict__ Q, ushort* __restrict__ Kt, ushort* __restrict__ V)
{
    const int b = blockIdx.y, n0 = blockIdx.x * 64;
    const int tid = threadIdx.x;
    const int w = tid >> 6, lane = tid & 63, l15 = lane & 15, q = lane >> 4;

    f32x4 acc[5][4];
    #pragma unroll
    for (int c5 = 0; c5 < 5; ++c5)
        #pragma unroll
        for (int nc = 0; nc < 4; ++nc) acc[c5][nc] = (f32x4)0.f;

    const float* xb = x + (size_t)b * CC * NN + n0;

    #pragma unroll
    for (int ks = 0; ks < 8; ++ks) {
        short8 af[5];
        #pragma unroll
        for (int c5 = 0; c5 < 5; ++c5)
            af[c5] = *(const short8*)&Wb[(w * 80 + c5 * 16 + l15) * CC + ks * 32 + q * 8];
        union { unsigned u[4]; short8 v; } bfu[4];
        #pragma unroll
        for (int nc = 0; nc < 4; ++nc) {
            const float* xp = xb + (size_t)(ks * 32 + q * 8) * NN + nc * 16 + l15;
            bfu[nc].u[0] = pack2(xp[0],          xp[(size_t)NN]);
            bfu[nc].u[1] = pack2(xp[2 * (size_t)NN], xp[3 * (size_t)NN]);
            bfu[nc].u[2] = pack2(xp[4 * (size_t)NN], xp[5 * (size_t)NN]);
            bfu[nc].u[3] = pack2(xp[6 * (size_t)NN], xp[7 * (size_t)NN]);
        }
        #pragma unroll
        for (int c5 = 0; c5 < 5; ++c5)
            #pragma unroll
            for (int nc = 0; nc < 4; ++nc)
                acc[c5][nc] = __builtin_amdgcn_mfma_f32_16x16x32_bf16(af[c5], bfu[nc].v, acc[c5][nc], 0, 0, 0);
    }

    #pragma unroll
    for (int c5 = 0; c5 < 5; ++c5) {
        const int o0 = w * 80 + c5 * 16;
        float bia[4];
        #pragma unroll
        for (int r = 0; r < 4; ++r) bia[r] = bias[o0 + q * 4 + r];
        if (o0 >= 64) {
            #pragma unroll
            for (int nc = 0; nc < 4; ++nc)
                #pragma unroll
                for (int r = 0; r < 4; ++r)
                    V[((size_t)b * CC + o0 - 64 + q * 4 + r) * NN + n0 + nc * 16 + l15] =
                        f2bf(acc[c5][nc][r] + bia[r]);
        } else {
            ushort* dst = (o0 < 32) ? Q : Kt;
            const float sc = (o0 < 32) ? LOG2E : 1.0f;   // exp2-domain Q
            const int oo = (o0 & 31) + q * 4;
            #pragma unroll
            for (int nc = 0; nc < 4; ++nc) {
                short4v h;
                #pragma unroll
                for (int r = 0; r < 4; ++r) h[r] = (short)f2bf((acc[c5][nc][r] + bia[r]) * sc);
                *(short4v*)&dst[((size_t)b * NN + n0 + nc * 16 + l15) * CKK + oo] = h;
            }
        }
    }
}

// ---------------- k2: flash attention v9 ----------------
// Unit-major V: vs2[buf][kh2][c][8]; unit (kh2=kh*2+h2, c) holds
// m = {16kh+4h2+0..3, 16kh+8+4h2+0..3} — exactly the PV A-frag under the
// k-perm slot(h2,j) -> m = 16kh + 8*(j>>2) + 4h2 + (j&3).
__global__ __launch_bounds__(256, 2) void attn_mfma_kernel(
    const ushort* __restrict__ Q, const ushort* __restrict__ K,
    const ushort* __restrict__ V,
    ushort* __restrict__ Op, float* __restrict__ Mp, float* __restrict__ Lp,
    int G, int NSEG)
{
    __shared__ __align__(16) ushort vs2[2][4][256][8];   // 2 x 16KB

    const int id = blockIdx.x;
    const int xcd = id & 7, ix = id >> 3;
    const int b = xcd >> 1;
    int g, row;
    if (G == 4) { g = ((xcd & 1) << 1) | (ix & 1); row = ix >> 1; }
    else        { g = xcd & 1;                     row = ix; }
    const int n0 = row * 128;

    const int tid = threadIdx.x;
    const int w = tid >> 6, lane = tid & 63;
    const int l31 = lane & 31, h2 = lane >> 5;
    const int n0w = n0 + w * 32;          // lane owns n = n0w + l31

    const size_t qrow = ((size_t)b * NN + n0w + l31) * CKK;
    short8 qB0 = *(const short8*)&Q[qrow + h2 * 8];
    short8 qB1 = *(const short8*)&Q[qrow + 16 + h2 * 8];

    f32x16 acc[8];                         // O^T: D[c = cb*32 + rowmap(r,h2)][n=l31]
    #pragma unroll
    for (int cb = 0; cb < 8; ++cb) acc[cb] = (f32x16)0.f;
    float m_i = -3.0e38f, l_p = 0.f;       // log2 domain

    const ushort* Kb = K + (size_t)b * NN * CKK;
    const size_t vgb = (size_t)b * CC * NN;
    const int m_start = g * NSEG;
    const int NT = NSEG / 32;

    const int srow = tid >> 2, sseg = tid & 3;
    const int kh2a = (sseg >> 1) << 1;     // 0 or 2
    const int sslot = (sseg & 1) << 2;     // 0 or 4

    // ---- prologue: S_0 + stage V(0), prefetch K(1), V(1) ----
    short8 kA0 = *(const short8*)&Kb[(size_t)(m_start + l31) * CKK + h2 * 8];
    short8 kA1 = *(const short8*)&Kb[(size_t)(m_start + l31) * CKK + 16 + h2 * 8];
    union { short8 v; short4v h[2]; } vr[4];
    #pragma unroll
    for (int i = 0; i < 4; ++i)
        vr[i].v = *(const short8*)&V[vgb + (size_t)(srow + i * 64) * NN + m_start + sseg * 8];
    f32x16 s = __builtin_amdgcn_mfma_f32_32x32x16_bf16(kA0, qB0, (f32x16)0.f, 0, 0, 0);
    s = __builtin_amdgcn_mfma_f32_32x32x16_bf16(kA1, qB1, s, 0, 0, 0);
    const int mi1 = (NT > 1) ? m_start + 32 : m_start;
    kA0 = *(const short8*)&Kb[(size_t)(mi1 + l31) * CKK + h2 * 8];
    kA1 = *(const short8*)&Kb[(size_t)(mi1 + l31) * CKK + 16 + h2 * 8];
    #pragma unroll
    for (int i = 0; i < 4; ++i) {
        const int c = srow + i * 64;
        *(short4v*)&vs2[0][kh2a + 0][c][sslot] = vr[i].h[0];
        *(short4v*)&vs2[0][kh2a + 1][c][sslot] = vr[i].h[1];
    }
    #pragma unroll
    for (int i = 0; i < 4; ++i)
        vr[i].v = *(const short8*)&V[vgb + (size_t)(srow + i * 64) * NN + mi1 + sseg * 8];
    __syncthreads();

    int cur = 0;
    for (int mt = 0; mt < NT; ++mt) {
        const bool more = (mt + 1 < NT);
        const int mi2 = (mt + 2 < NT) ? m_start + (mt + 2) * 32 : m_start;

        // ---- S_{t+1} early: MFMA latency hides under softmax_t (VALU) ----
        f32x16 sn = __builtin_amdgcn_mfma_f32_32x32x16_bf16(kA0, qB0, (f32x16)0.f, 0, 0, 0);
        sn = __builtin_amdgcn_mfma_f32_32x32x16_bf16(kA1, qB1, sn, 0, 0, 0);
        kA0 = *(const short8*)&Kb[(size_t)(mi2 + l31) * CKK + h2 * 8];
        kA1 = *(const short8*)&Kb[(size_t)(mi2 + l31) * CKK + 16 + h2 * 8];

        // ---- softmax on s (log2 domain), max3-fused reduce ----
        float t0 = fmaxf(fmaxf(s[0],  s[1]),  s[2]);
        float t1 = fmaxf(fmaxf(s[3],  s[4]),  s[5]);
        float t2 = fmaxf(fmaxf(s[6],  s[7]),  s[8]);
        float t3 = fmaxf(fmaxf(s[9],  s[10]), s[11]);
        float t4 = fmaxf(fmaxf(s[12], s[13]), s[14]);
        float mx = fmaxf(fmaxf(fmaxf(t0, t1), t2), fmaxf(fmaxf(t3, t4), s[15]));
        mx = fmaxf(mx, __shfl_xor(mx, 32));
        const bool resc = mx > m_i + 8.f;            // defer-max THR=8
        const float mn = resc ? mx : m_i;
        const float al = resc ? exp2fast(m_i - mx) : 1.f;
        // fused exp + sum + pack (s dies in place; no pp[] array)
        union { unsigned u[8]; short8 v[2]; } P;
        float sum0 = 0.f, sum1 = 0.f;
        #pragma unroll
        for (int g2 = 0; g2 < 8; ++g2) {
            const float plo = exp2fast(s[2 * g2]     - mn);
            const float phi = exp2fast(s[2 * g2 + 1] - mn);
            if (g2 & 1) sum1 += plo + phi; else sum0 += plo + phi;
            P.u[g2] = pack2(plo, phi);
        }
        l_p = l_p * al + (sum0 + sum1);
        m_i = mn;
        if (__any(resc)) {                           // alpha per-lane exact (n = l31)
            #pragma unroll
            for (int cb = 0; cb < 8; ++cb) acc[cb] *= al;
        }

        // ---- PV: A-frags are single b128 units, contiguous per 16-lane grp ----
        __builtin_amdgcn_s_setprio(1);
        #pragma unroll
        for (int cb = 0; cb < 8; ++cb) {
            const short8 A0 = *(const short8*)&vs2[cur][h2][cb * 32 + l31][0];
            const short8 A1 = *(const short8*)&vs2[cur][2 + h2][cb * 32 + l31][0];
            acc[cb] = __builtin_amdgcn_mfma_f32_32x32x16_bf16(A0, P.v[0], acc[cb], 0, 0, 0);
            acc[cb] = __builtin_amdgcn_mfma_f32_32x32x16_bf16(A1, P.v[1], acc[cb], 0, 0, 0);
        }
        __builtin_amdgcn_s_setprio(0);

        // ---- stage next V tile; one barrier/tile; issue V(t+2) loads ----
        if (more) {
            #pragma unroll
            for (int i = 0; i < 4; ++i) {
                const int c = srow + i * 64;
                *(short4v*)&vs2[cur ^ 1][kh2a + 0][c][sslot] = vr[i].h[0];
                *(short4v*)&vs2[cur ^ 1][kh2a + 1][c][sslot] = vr[i].h[1];
            }
            __syncthreads();
            #pragma unroll
            for (int i = 0; i < 4; ++i)
                vr[i].v = *(const short8*)&V[vgb + (size_t)(srow + i * 64) * NN + mi2 + sseg * 8];
        }
        s = sn; cur ^= 1;
    }

    // ---- epilogue ----
    float l = l_p + __shfl_xor(l_p, 32);
    const float linv = 1.f / l;
    if (h2 == 0) {
        const size_t idx = (size_t)(g * BB + b) * NN + n0w + l31;
        Mp[idx] = m_i;                               // log2 domain
        Lp[idx] = l;
    }
    ushort* ob = Op + (size_t)(g * BB + b) * CC * NN;
    #pragma unroll
    for (int cb = 0; cb < 8; ++cb)
        #pragma unroll
        for (int r = 0; r < 16; ++r) {
            const int c = cb * 32 + (r & 3) + 8 * (r >> 2) + 4 * h2;
            ob[(size_t)c * NN + n0w + l31] = f2bf(acc[cb][r] * linv);
        }
}

// ---------------- k3: combine, vectorized (log2-domain Mp) ----------------
template<int G>
__global__ __launch_bounds__(256) void combine_kernel(
    const ushort* __restrict__ Op, const float* __restrict__ Mp,
    const float* __restrict__ Lp, const float* __restrict__ x,
    const float* __restrict__ gamma, float* __restrict__ out)
{
    const int gid = blockIdx.x * 256 + threadIdx.x;   // 0 .. B*C*(N/8)-1
    const int grp   = gid & (NN / 8 - 1);             // 0..511
    const int rowid = gid >> 9;                       // b*CC + c
    const int b = rowid >> 8;
    const int c = rowid & (CC - 1);
    const int n0 = grp * 8;

    f32x4 mp[G][2], lp[G][2];
    #pragma unroll
    for (int g = 0; g < G; ++g) {
        const size_t base = (size_t)(g * BB + b) * NN + n0;
        mp[g][0] = *(const f32x4*)&Mp[base];
        mp[g][1] = *(const f32x4*)&Mp[base + 4];
        lp[g][0] = *(const f32x4*)&Lp[base];
        lp[g][1] = *(const f32x4*)&Lp[base + 4];
    }
    float wgt[G][8];
    #pragma unroll
    for (int h = 0; h < 2; ++h) {
        #pragma unroll
        for (int j = 0; j < 4; ++j) {
            float M = -3.0e38f;
            #pragma unroll
            for (int g = 0; g < G; ++g) M = fmaxf(M, mp[g][h][j]);
            float ws = 0.f;
            #pragma unroll
            for (int g = 0; g < G; ++g) {
                const float wv = lp[g][h][j] * exp2fast(mp[g][h][j] - M);
                wgt[g][h * 4 + j] = wv;
                ws += wv;
            }
            const float inv = 1.f / ws;
            #pragma unroll
            for (int g = 0; g < G; ++g) wgt[g][h * 4 + j] *= inv;
        }
    }

    short8 opv[G];
    #pragma unroll
    for (int g = 0; g < G; ++g)
        opv[g] = *(const short8*)&Op[((size_t)(g * BB + b) * CC + c) * NN + n0];

    const size_t xbase = ((size_t)b * CC + c) * NN + n0;
    const f32x4 x0 = *(const f32x4*)&x[xbase];
    const f32x4 x1 = *(const f32x4*)&x[xbase + 4];
    const float gm = gamma[0];

    f32x4 o0, o1;
    #pragma unroll
    for (int j = 0; j < 4; ++j) {
        float a = 0.f, bsum = 0.f;
        #pragma unroll
        for (int g = 0; g < G; ++g) {
            a    += wgt[g][j]     * bf2f((ushort)opv[g][j]);
            bsum += wgt[g][4 + j] * bf2f((ushort)opv[g][4 + j]);
        }
        o0[j] = gm * a + x0[j];
        o1[j] = gm * bsum + x1[j];
    }
    *(f32x4*)&out[xbase]     = o0;
    *(f32x4*)&out[xbase + 4] = o1;
}

extern "C" void kernel_launch(void* const* d_in, const int* in_sizes, int n_in,
                              void* d_out, int out_size, void* d_ws, size_t ws_size,
                              hipStream_t stream) {
    const float* x     = (const float*)d_in[0];
    const float* Wq    = (const float*)d_in[1];
    const float* bq    = (const float*)d_in[2];
    const float* Wk    = (const float*)d_in[3];
    const float* bk    = (const float*)d_in[4];
    const float* Wv    = (const float*)d_in[5];
    const float* bv    = (const float*)d_in[6];
    const float* gamma = (const float*)d_in[7];
    float* out = (float*)d_out;

    char* p = (char*)d_ws;
    ushort* Wb   = (ushort*)(p);                 // 163840
    float*  bias = (float*) (p + 163840);        // 1280   -> 165120
    ushort* Qb   = (ushort*)(p + 165120);        // 1048576 -> 1213696
    ushort* Kb   = (ushort*)(p + 1213696);       // 1048576 -> 2262272
    ushort* Vc   = (ushort*)(p + 2262272);       // 8388608 -> 10650880
    float*  Mpb  = (float*) (p + 10650880);      // 262144  -> 10913024
    float*  Lpb  = (float*) (p + 10913024);      // 262144  -> 11175168
    ushort* Opb  = (ushort*)(p + 11175168);      // G*8388608
    // G=4 total: 44,729,600 B; G=2 total: 27,952,384 B
    const int G = (ws_size >= (size_t)44729600) ? 4 : 2;

    pack_w_kernel<<<dim3(320), 256, 0, stream>>>(Wq, bq, Wk, bk, Wv, bv, Wb, bias);
    qkv_mfma_kernel<<<dim3(NN / 64, BB), 256, 0, stream>>>(Wb, bias, x, Qb, Kb, Vc);
    attn_mfma_kernel<<<dim3(128 * G), 256, 0, stream>>>(Qb, Kb, Vc, Opb, Mpb, Lpb, G, NN / G);
    const int cblocks = BB * CC * (NN / 8) / 256;   // 2048
    if (G == 4)
        combine_kernel<4><<<dim3(cblocks), 256, 0, stream>>>(Opb, Mpb, Lpb, x, gamma, out);
    else
        combine_kernel<2><<<dim3(cblocks), 256, 0, stream>>>(Opb, Mpb, Lpb, x, gamma, out);
}